// Round 10
// baseline (373.721 us; speedup 1.0000x reference)
//
#include <hip/hip_runtime.h>
#include <hip/hip_fp16.h>

#define N_NODES 307
#define T_LEN   6000
#define L1      5991
#define L2      5982
#define ED      96
#define FDIM    95712
#define NCH2    16
#define LCPC    16                  // l-chunks per channel
#define CHL     374                 // rows per l-chunk (last = 372)
#define K5CH    (NCH2 * LCPC)       // 256 K-chunks, channel-pure
#define K5KS    12                  // ceil(374/32)

// ---- workspace layout (float/u32 offsets) ----
// consts: [0..7]=s1 [8..15]=t1 [16..31]=s2 [32..47]=t2
static const size_t WS_P1 = 256;                    // conv1 stat partials: 375*16
static const size_t WS_P2 = 8192;                   // conv2 stat partials: 3740*32
static const size_t WS_CS = 131072;                 // colsum partials: 256*96 = 24576
static const size_t WS_NF = 155648;                 // node_feat 307*96
static const size_t WS_SP = 188416;                 // s_proj
static const size_t WS_RP = 221184;                 // r_proj
static const size_t WS_A2 = 262144;                 // a2 PACKED u32: 95712*320
static const size_t WS_FP = 262144 + 30627840ull;   // fc partials: 256*96*320 = 7,864,320
static const size_t WS_BP = 30889984ull + 7864320ull; // packed fcw u32: 95712*96 = 9,188,352
// total = 48,078,336 elems ~= 192.3 MB

typedef _Float16 half8 __attribute__((ext_vector_type(8)));
typedef float f32x4 __attribute__((ext_vector_type(4)));

union U4H8 { uint4 u; half8 h; };

// pack fp32 -> (f16 hi | f16 lo<<16), x ~= hi + lo/2048
__device__ __forceinline__ unsigned int pack2h(float x) {
  __half h = __float2half(x);
  float r = (x - __half2float(h)) * 2048.0f;
  __half l = __float2half(r);
  return (unsigned int)__half_as_ushort(h) | ((unsigned int)__half_as_ushort(l) << 16);
}

// XOR-swizzled LDS offset: 32-u32 rows, permute 16B chunks.
// chunk' = chunk ^ (row&7) ^ ((row>>3)&7)
__device__ __forceinline__ int swz(int row, int col) {
  int c = col >> 2, w = col & 3;
  int cs = c ^ (row & 7) ^ ((row >> 3) & 7);
  return row * 32 + cs * 4 + w;
}

// ================= K1: conv1 + relu, channel stats only =================
__global__ __launch_bounds__(320) void dgl_k1_conv1_stats(
    const float* __restrict__ nfeat, const float* __restrict__ w1,
    const float* __restrict__ b1, float* __restrict__ ws) {
  __shared__ float sw1[80], sb1[8];
  __shared__ float sred[5][16];
  int tid = threadIdx.x;
  if (tid < 80) sw1[tid] = w1[tid];
  if (tid < 8)  sb1[tid] = b1[tid];
  __syncthreads();
  int l0 = blockIdx.x * 16;
  int n = tid;
  bool nv = n < N_NODES;
  float xx[26];
#pragma unroll
  for (int j = 0; j < 26; ++j) {
    int t = l0 + j;
    xx[j] = (nv && t < T_LEN) ? nfeat[(size_t)t * N_NODES + n] : 0.f;
  }
  float s[8], q[8];
#pragma unroll
  for (int c = 0; c < 8; ++c) { s[c] = 0.f; q[c] = 0.f; }
#pragma unroll
  for (int dl = 0; dl < 16; ++dl) {
    int l = l0 + dl;
    if (nv && l < L1) {
#pragma unroll
      for (int c = 0; c < 8; ++c) {
        float r = sb1[c];
#pragma unroll
        for (int k = 0; k < 10; ++k) r = fmaf(xx[dl + k], sw1[c * 10 + k], r);
        float z = fmaxf(r, 0.f);
        s[c] += z; q[c] += z * z;
      }
    }
  }
  int wv = tid >> 6, ln = tid & 63;
#pragma unroll
  for (int c = 0; c < 8; ++c) {
    float vs = s[c], vq = q[c];
    for (int o = 32; o; o >>= 1) { vs += __shfl_down(vs, o, 64); vq += __shfl_down(vq, o, 64); }
    if (ln == 0) { sred[wv][c] = vs; sred[wv][8 + c] = vq; }
  }
  __syncthreads();
  if (tid < 16) {
    float t = 0.f;
    for (int w = 0; w < 5; ++w) t += sred[w][tid];
    ws[WS_P1 + (size_t)blockIdx.x * 16 + tid] = t;
  }
}

// ================= K2: finalize bn1 =================
__global__ void dgl_k2_fin1(const float* __restrict__ g1, const float* __restrict__ b1,
                            float* __restrict__ ws) {
  __shared__ double sd[16];
  int tid = threadIdx.x;
  if (tid < 16) {
    double a = 0.0;
    for (int j = 0; j < 375; ++j) a += (double)ws[WS_P1 + (size_t)j * 16 + tid];
    sd[tid] = a;
  }
  __syncthreads();
  if (tid < 8) {
    double cnt = (double)N_NODES * (double)L1;
    double m = sd[tid] / cnt;
    double v = sd[tid + 8] / cnt - m * m;
    double inv = 1.0 / sqrt(v + 1e-5);
    ws[tid]     = (float)((double)g1[tid] * inv);
    ws[8 + tid] = (float)((double)b1[tid] - (double)g1[tid] * inv * m);
  }
}

// ================= K3: fused conv1+bn1 -> conv2 + relu -> a2 (PACKED) + stats =================
__global__ __launch_bounds__(256, 4) void dgl_k3_conv2(
    const float* __restrict__ nfeat, const float* __restrict__ w1, const float* __restrict__ b1,
    const float* __restrict__ w2, const float* __restrict__ b2, float* __restrict__ ws) {
  __shared__ float sx[26][64];
  __shared__ float sz[4][17][64];
  __shared__ float sw2[1280], sw1[80], sb1[8], sb2[16], ss1[8], st1[8];
  __shared__ float wpart[4][8];
  int tid = threadIdx.x;
  int lane = tid & 63, g = tid >> 6;
  int l0 = blockIdx.x * 8, n0 = blockIdx.y * 64;
  unsigned int* a2u = (unsigned int*)(ws + WS_A2);
  for (int i = tid; i < 1280; i += 256) sw2[i] = w2[i];
  if (tid < 80) sw1[tid] = w1[tid];
  if (tid < 8)  { sb1[tid] = b1[tid]; ss1[tid] = ws[tid]; st1[tid] = ws[8 + tid]; }
  if (tid < 16) sb2[tid] = b2[tid];
  for (int i = tid; i < 26 * 64; i += 256) {
    int j = i >> 6, l2 = i & 63;
    int t = l0 + j, nn = n0 + l2;
    sx[j][l2] = (t < T_LEN && nn < N_NODES) ? nfeat[(size_t)t * N_NODES + nn] : 0.f;
  }
  float acc[4][8];
#pragma unroll
  for (int qq = 0; qq < 4; ++qq)
#pragma unroll
    for (int dl = 0; dl < 8; ++dl) acc[qq][dl] = 0.f;
  __syncthreads();
#pragma unroll 1
  for (int p = 0; p < 2; ++p) {
    {
      int c = p * 4 + g;
#pragma unroll
      for (int lz = 0; lz < 17; ++lz) {
        float r = sb1[c];
#pragma unroll
        for (int k = 0; k < 10; ++k) r = fmaf(sx[lz + k][lane], sw1[c * 10 + k], r);
        sz[g][lz][lane] = fmaf(ss1[c], fmaxf(r, 0.f), st1[c]);
      }
    }
    __syncthreads();
#pragma unroll
    for (int c4 = 0; c4 < 4; ++c4) {
      int cin = p * 4 + c4;
      float zr[17];
#pragma unroll
      for (int t = 0; t < 17; ++t) zr[t] = sz[c4][t][lane];
#pragma unroll
      for (int k = 0; k < 10; ++k) {
#pragma unroll
        for (int qq = 0; qq < 4; ++qq) {
          float w = sw2[(g * 4 + qq) * 80 + cin * 10 + k];
#pragma unroll
          for (int dl = 0; dl < 8; ++dl) acc[qq][dl] = fmaf(zr[dl + k], w, acc[qq][dl]);
        }
      }
    }
    __syncthreads();
  }
  int n = n0 + lane;
  bool nv = n < N_NODES;
  float s4[4] = {0.f, 0.f, 0.f, 0.f}, q4[4] = {0.f, 0.f, 0.f, 0.f};
#pragma unroll
  for (int qq = 0; qq < 4; ++qq) {
    int c2 = g * 4 + qq;
#pragma unroll
    for (int dl = 0; dl < 8; ++dl) {
      int l = l0 + dl;
      float v = 0.f;
      if (nv && l < L2) v = fmaxf(acc[qq][dl] + sb2[c2], 0.f);
      if (l < L2) a2u[((size_t)c2 * L2 + l) * 320 + n] = pack2h(v);
      s4[qq] += v; q4[qq] += v * v;
    }
  }
#pragma unroll
  for (int qq = 0; qq < 4; ++qq) {
    float vs = s4[qq], vq = q4[qq];
    for (int o = 32; o; o >>= 1) { vs += __shfl_down(vs, o, 64); vq += __shfl_down(vq, o, 64); }
    if (lane == 0) { wpart[g][qq] = vs; wpart[g][4 + qq] = vq; }
  }
  __syncthreads();
  if (tid < 32) {
    int c2 = tid & 15; bool isq = tid >= 16;
    float v = wpart[c2 >> 2][(isq ? 4 : 0) + (c2 & 3)];
    ws[WS_P2 + ((size_t)blockIdx.y * gridDim.x + blockIdx.x) * 32 + tid] = v;
  }
}

// ================= K4: finalize bn2 =================
__global__ __launch_bounds__(512) void dgl_k4_fin2(const float* __restrict__ g2,
                                                   const float* __restrict__ b2,
                                                   float* __restrict__ ws) {
  __shared__ double dd[32][17];
  int tid = threadIdx.x;
  int v = tid >> 4, p = tid & 15;
  double a = 0.0;
  for (int j = p; j < 3740; j += 16) a += (double)ws[WS_P2 + (size_t)j * 32 + v];
  dd[v][p] = a;
  __syncthreads();
  if (tid < 32) {
    double s = 0.0;
    for (int pp = 0; pp < 16; ++pp) s += dd[tid][pp];
    dd[tid][16] = s;
  }
  __syncthreads();
  if (tid < 16) {
    double cnt = (double)N_NODES * (double)L2;
    double m = dd[tid][16] / cnt;
    double var = dd[tid + 16][16] / cnt - m * m;
    double inv = 1.0 / sqrt(var + 1e-5);
    ws[16 + tid] = (float)((double)g2[tid] * inv);
    ws[32 + tid] = (float)((double)b2[tid] - (double)g2[tid] * inv * m);
  }
}

// ================= K4b: colsum partials of fc_w + packed fcw copy =================
__global__ __launch_bounds__(384) void dgl_k4b_colsum(const float* __restrict__ fcw,
                                                      float* __restrict__ ws) {
  __shared__ float red[4][96];
  int b = blockIdx.x;                 // 0..255
  int c = b / LCPC, lc = b % LCPC;
  int clen = (lc == LCPC - 1) ? (L2 - CHL * (LCPC - 1)) : CHL;
  size_t fb = (size_t)c * L2 + (size_t)lc * CHL;
  unsigned int* bpu = (unsigned int*)(ws + WS_BP);
  int tid = threadIdx.x, rg = tid / 96, e = tid % 96;
  float a = 0.f;
  for (int r = rg; r < clen; r += 4) {
    float v = fcw[(fb + r) * 96 + e];
    bpu[(fb + r) * 96 + e] = pack2h(v);
    a += v;
  }
  red[rg][e] = a;
  __syncthreads();
  if (tid < 96) {
    float t = red[0][tid] + red[1][tid] + red[2][tid] + red[3][tid];
    ws[WS_CS + (size_t)b * 96 + tid] = t;
  }
}

// ================= K5: split-K GEMM via f16x2-split MFMA, pre-packed operands =================
// y = Ahi*Bhi + (Ahi*Blo + Alo*Bhi)/2048. Staging = raw u32 copies (no pack VALU).
__global__ __launch_bounds__(256) void dgl_k5_fc(float* __restrict__ ws) {
  __shared__ unsigned int Ahl[64 * 32];   // [n][k32], XOR-swizzled chunks
  __shared__ unsigned int Bhl[96 * 32];   // [e][k32], XOR-swizzled chunks
  int tid = threadIdx.x;
  int ch = blockIdx.x;
  int c = ch / LCPC, lc = ch % LCPC;
  int clen = (lc == LCPC - 1) ? (L2 - CHL * (LCPC - 1)) : CHL;
  size_t fb = (size_t)c * L2 + (size_t)lc * CHL;
  int n0 = blockIdx.y * 64;
  const unsigned int* a2u = (const unsigned int*)(ws + WS_A2);
  const unsigned int* bpu = (const unsigned int*)(ws + WS_BP);
  int wv = tid >> 6, lane = tid & 63;
  int m = lane & 15, g = lane >> 4;

  f32x4 acc1[6], acc2[6];
#pragma unroll
  for (int t = 0; t < 6; ++t) {
    acc1[t] = (f32x4){0.f, 0.f, 0.f, 0.f};
    acc2[t] = (f32x4){0.f, 0.f, 0.f, 0.f};
  }
  int ka = tid >> 3, n8 = (tid & 7) * 8;            // A: row ka, cols n8..n8+7
  const uint4 zu4 = make_uint4(0u, 0u, 0u, 0u);

#pragma unroll 1
  for (int ks = 0; ks < K5KS; ++ks) {
    int r0 = ks * 32;
    // ---- stage A (32k x 64n), raw u32 copy, transpose into [n][k] ----
    {
      int rr = r0 + ka;
      bool ok = rr < clen;
      const unsigned int* src = a2u + (fb + rr) * 320 + n0 + n8;
      uint4 va = ok ? *(const uint4*)(src) : zu4;
      uint4 vb = ok ? *(const uint4*)(src + 4) : zu4;
      Ahl[swz(n8 + 0, ka)] = va.x; Ahl[swz(n8 + 1, ka)] = va.y;
      Ahl[swz(n8 + 2, ka)] = va.z; Ahl[swz(n8 + 3, ka)] = va.w;
      Ahl[swz(n8 + 4, ka)] = vb.x; Ahl[swz(n8 + 5, ka)] = vb.y;
      Ahl[swz(n8 + 6, ka)] = vb.z; Ahl[swz(n8 + 7, ka)] = vb.w;
    }
    // ---- stage B (32k x 96e), raw u32 copy, transpose into [e][k] ----
#pragma unroll
    for (int i = 0; i < 3; ++i) {
      int fl = tid + i * 256;
      int kb = fl / 24, e4 = (fl % 24) * 4;
      int rr = r0 + kb;
      bool ok = rr < clen;
      uint4 v = ok ? *(const uint4*)(bpu + (fb + rr) * 96 + e4) : zu4;
      Bhl[swz(e4 + 0, kb)] = v.x; Bhl[swz(e4 + 1, kb)] = v.y;
      Bhl[swz(e4 + 2, kb)] = v.z; Bhl[swz(e4 + 3, kb)] = v.w;
    }
    __syncthreads();
    // ---- A fragment (row m of wave's 16n, k = 8g..8g+7) ----
    int ar = 16 * wv + m;
    uint4 a0 = *(const uint4*)&Ahl[swz(ar, 8 * g)];
    uint4 a1 = *(const uint4*)&Ahl[swz(ar, 8 * g + 4)];
    U4H8 Ahi, Alo;
    Ahi.u = make_uint4((a0.x & 0xFFFFu) | (a0.y << 16), (a0.z & 0xFFFFu) | (a0.w << 16),
                       (a1.x & 0xFFFFu) | (a1.y << 16), (a1.z & 0xFFFFu) | (a1.w << 16));
    Alo.u = make_uint4((a0.x >> 16) | (a0.y & 0xFFFF0000u), (a0.z >> 16) | (a0.w & 0xFFFF0000u),
                       (a1.x >> 16) | (a1.y & 0xFFFF0000u), (a1.z >> 16) | (a1.w & 0xFFFF0000u));
#pragma unroll
    for (int t = 0; t < 6; ++t) {
      int br = 16 * t + m;
      uint4 b0 = *(const uint4*)&Bhl[swz(br, 8 * g)];
      uint4 b1 = *(const uint4*)&Bhl[swz(br, 8 * g + 4)];
      U4H8 Bhi, Blo;
      Bhi.u = make_uint4((b0.x & 0xFFFFu) | (b0.y << 16), (b0.z & 0xFFFFu) | (b0.w << 16),
                         (b1.x & 0xFFFFu) | (b1.y << 16), (b1.z & 0xFFFFu) | (b1.w << 16));
      Blo.u = make_uint4((b0.x >> 16) | (b0.y & 0xFFFF0000u), (b0.z >> 16) | (b0.w & 0xFFFF0000u),
                         (b1.x >> 16) | (b1.y & 0xFFFF0000u), (b1.z >> 16) | (b1.w & 0xFFFF0000u));
      acc1[t] = __builtin_amdgcn_mfma_f32_16x16x32_f16(Ahi.h, Bhi.h, acc1[t], 0, 0, 0);
      acc2[t] = __builtin_amdgcn_mfma_f32_16x16x32_f16(Ahi.h, Blo.h, acc2[t], 0, 0, 0);
      acc2[t] = __builtin_amdgcn_mfma_f32_16x16x32_f16(Alo.h, Bhi.h, acc2[t], 0, 0, 0);
    }
    __syncthreads();
  }
  // ---- epilogue: D col = lane&15 -> e, row = 4g + r -> n-local ----
  float* fp = ws + WS_FP;
#pragma unroll
  for (int t = 0; t < 6; ++t) {
    int e = 16 * t + m;
#pragma unroll
    for (int r = 0; r < 4; ++r) {
      int n = n0 + 16 * wv + 4 * g + r;
      fp[((size_t)ch * 96 + e) * 320 + n] = acc1[t][r] + acc2[t][r] * (1.0f / 2048.0f);
    }
  }
}

// ================= K6: fp64 combine (s2*P + t2*colsum + fcb) + relu + bn3 =================
__global__ __launch_bounds__(320) void dgl_k6_bn3(const float* __restrict__ fcb,
                                                  const float* __restrict__ g3,
                                                  const float* __restrict__ b3,
                                                  float* __restrict__ ws) {
  int e = blockIdx.x, tid = threadIdx.x;
  __shared__ double s2d[16], csd[16];
  __shared__ double rs[5], rq[5];
  __shared__ float mb[2];
  if (tid < 16) {
    s2d[tid] = (double)ws[16 + tid];
    double a = 0.0;
#pragma unroll
    for (int lc = 0; lc < LCPC; ++lc)
      a += (double)ws[WS_CS + (size_t)(tid * LCPC + lc) * 96 + e];
    csd[tid] = a * (double)ws[32 + tid];   // t2[c] * colsum_c[e]
  }
  __syncthreads();
  const float* fp = ws + WS_FP;
  double a = 0.0;
#pragma unroll 2
  for (int c = 0; c < 16; ++c) {
    double pc = 0.0;
    for (int lc = 0; lc < LCPC; ++lc) {
      int ch = c * LCPC + lc;
      pc += (double)fp[((size_t)ch * 96 + e) * 320 + tid];
    }
    a += s2d[c] * pc;
  }
  double cst = 0.0;
#pragma unroll
  for (int c = 0; c < 16; ++c) cst += csd[c];
  float x = fmaxf((float)(a + cst) + fcb[e], 0.f);
  if (tid >= N_NODES) x = 0.f;
  double s = (double)x, q = (double)x * (double)x;
  int wv = tid >> 6, ln = tid & 63;
  for (int o = 32; o; o >>= 1) { s += __shfl_down(s, o, 64); q += __shfl_down(q, o, 64); }
  if (ln == 0) { rs[wv] = s; rq[wv] = q; }
  __syncthreads();
  if (tid == 0) {
    double S = 0.0, Q = 0.0;
    for (int w = 0; w < 5; ++w) { S += rs[w]; Q += rq[w]; }
    double m = S / (double)N_NODES;
    double var = Q / (double)N_NODES - m * m;
    mb[0] = (float)m; mb[1] = (float)(1.0 / sqrt(var + 1e-5));
  }
  __syncthreads();
  if (tid < N_NODES)
    ws[WS_NF + (size_t)tid * 96 + e] = g3[e] * (x - mb[0]) * mb[1] + b3[e];
}

// ================= K7: s_proj / r_proj =================
__global__ __launch_bounds__(192) void dgl_k7_proj(const float* __restrict__ fow,
                                                   float* __restrict__ ws) {
  __shared__ float sh[96];
  int nI = blockIdx.x, tid = threadIdx.x;
  if (tid < 96) sh[tid] = ws[WS_NF + (size_t)nI * 96 + tid];
  __syncthreads();
  int col = tid % 96, half = tid / 96;
  float a = 0.f;
#pragma unroll 8
  for (int d = 0; d < 96; ++d) a = fmaf(sh[d], fow[(size_t)(half * 96 + d) * 96 + col], a);
  ws[(half ? WS_RP : WS_SP) + (size_t)nI * 96 + col] = a;
}

// ================= K8: edge relu + logits + gumbel + hard argmax -> adj =================
__global__ __launch_bounds__(256) void dgl_k8_edge(const float* __restrict__ fob,
                                                   const float* __restrict__ fcatw,
                                                   const float* __restrict__ fcatb,
                                                   const float* __restrict__ unif,
                                                   const float* __restrict__ ws,
                                                   float* __restrict__ out) {
  __shared__ float rp[16][100], sp[16][100], bb[96], wa[96], wb[96];
  int tid = threadIdx.x;
  int i0 = blockIdx.y * 16, j0 = blockIdx.x * 16;
  for (int idx = tid; idx < 16 * 96; idx += 256) {
    int r = idx / 96, e = idx % 96;
    int ii = i0 + r, jj = j0 + r;
    rp[r][e] = (ii < N_NODES) ? ws[WS_RP + (size_t)ii * 96 + e] : 0.f;
    sp[r][e] = (jj < N_NODES) ? ws[WS_SP + (size_t)jj * 96 + e] : 0.f;
  }
  if (tid < 96) { bb[tid] = fob[tid]; wa[tid] = fcatw[2 * tid]; wb[tid] = fcatw[2 * tid + 1]; }
  __syncthreads();
  int il = tid >> 4, jl = tid & 15;
  int i = i0 + il, j = j0 + jl;
  float a0 = 0.f, a1 = 0.f;
#pragma unroll 4
  for (int e = 0; e < 96; ++e) {
    float ef = fmaxf(rp[il][e] + sp[jl][e] + bb[e], 0.f);
    a0 = fmaf(ef, wa[e], a0);
    a1 = fmaf(ef, wb[e], a1);
  }
  if (i < N_NODES && j < N_NODES) {
    size_t ue = ((size_t)i * N_NODES + j) * 2;
    float g0 = -logf(-logf(unif[ue] + 1e-20f) + 1e-20f);
    float g1 = -logf(-logf(unif[ue + 1] + 1e-20f) + 1e-20f);
    float z0 = a0 + fcatb[0] + g0;
    float z1 = a1 + fcatb[1] + g1;
    out[(size_t)i * N_NODES + j] = (i == j) ? 0.f : ((z0 >= z1) ? 1.f : 0.f);
  }
}

extern "C" void kernel_launch(void* const* d_in, const int* in_sizes, int n_in,
                              void* d_out, int out_size, void* d_ws, size_t ws_size,
                              hipStream_t stream) {
  const float* nfeat = (const float*)d_in[1];
  const float* w1    = (const float*)d_in[2];
  const float* b1    = (const float*)d_in[3];
  const float* w2    = (const float*)d_in[4];
  const float* b2    = (const float*)d_in[5];
  const float* g1    = (const float*)d_in[6];
  const float* bb1   = (const float*)d_in[7];
  const float* g2    = (const float*)d_in[8];
  const float* bb2   = (const float*)d_in[9];
  const float* g3    = (const float*)d_in[10];
  const float* bb3   = (const float*)d_in[11];
  const float* fcw   = (const float*)d_in[12];
  const float* fcb   = (const float*)d_in[13];
  const float* fow   = (const float*)d_in[14];
  const float* fob   = (const float*)d_in[15];
  const float* fcatw = (const float*)d_in[16];
  const float* fcatb = (const float*)d_in[17];
  const float* unif  = (const float*)d_in[18];
  float* ws  = (float*)d_ws;
  float* out = (float*)d_out;

  dgl_k4b_colsum<<<dim3(K5CH), dim3(384), 0, stream>>>(fcw, ws);
  dgl_k1_conv1_stats<<<dim3(375), dim3(320), 0, stream>>>(nfeat, w1, b1, ws);
  dgl_k2_fin1<<<dim3(1), dim3(64), 0, stream>>>(g1, bb1, ws);
  dgl_k3_conv2<<<dim3(748, 5), dim3(256), 0, stream>>>(nfeat, w1, b1, w2, b2, ws);
  dgl_k4_fin2<<<dim3(1), dim3(512), 0, stream>>>(g2, bb2, ws);
  dgl_k5_fc<<<dim3(K5CH, 5), dim3(256), 0, stream>>>(ws);
  dgl_k6_bn3<<<dim3(96), dim3(320), 0, stream>>>(fcb, g3, bb3, ws);
  dgl_k7_proj<<<dim3(307), dim3(192), 0, stream>>>(fow, ws);
  dgl_k8_edge<<<dim3(20, 20), dim3(256), 0, stream>>>(fob, fcatw, fcatb, unif, ws, out);
}

// Round 11
// 282.301 us; speedup vs baseline: 1.3238x; 1.3238x over previous
//
#include <hip/hip_runtime.h>
#include <hip/hip_fp16.h>

#define N_NODES 307
#define T_LEN   6000
#define L1      5991
#define L2      5982
#define ED      96
#define FDIM    95712
#define NCH2    16
#define LCPC    16                  // l-chunks per channel
#define CHL     374                 // rows per l-chunk (last = 372)
#define K5CH    (NCH2 * LCPC)       // 256 K-chunks, channel-pure

// ---- workspace layout (float/u32 offsets) ---- (identical to R10)
static const size_t WS_P1 = 256;                    // conv1 stat partials: 375*16
static const size_t WS_P2 = 8192;                   // conv2 stat partials: 3740*32
static const size_t WS_CS = 131072;                 // colsum partials: 256*96
static const size_t WS_NF = 155648;                 // node_feat 307*96
static const size_t WS_SP = 188416;                 // s_proj
static const size_t WS_RP = 221184;                 // r_proj
static const size_t WS_A2 = 262144;                 // a2 PACKED u32: 95712*320
static const size_t WS_FP = 262144 + 30627840ull;   // fc partials: 256*96*320
static const size_t WS_BP = 30889984ull + 7864320ull; // packed fcw u32: 95712*96
// total ~= 192.3 MB

typedef _Float16 half8 __attribute__((ext_vector_type(8)));
typedef float f32x4 __attribute__((ext_vector_type(4)));

union U4H8 { uint4 u; half8 h; };

// pack fp32 -> (f16 hi | f16 lo<<16), x ~= hi + lo/2048
__device__ __forceinline__ unsigned int pack2h(float x) {
  __half h = __float2half(x);
  float r = (x - __half2float(h)) * 2048.0f;
  __half l = __float2half(r);
  return (unsigned int)__half_as_ushort(h) | ((unsigned int)__half_as_ushort(l) << 16);
}

// B-LDS swizzle: [e][k] rows of 192 u32 (192%32==0), 16B-chunk XOR by e&7.
__device__ __forceinline__ int swzB(int e, int k) {
  return e * 192 + (((k >> 2) ^ (e & 7)) << 2) + (k & 3);
}

// ================= K1: conv1 + relu, channel stats only =================
__global__ __launch_bounds__(320) void dgl_k1_conv1_stats(
    const float* __restrict__ nfeat, const float* __restrict__ w1,
    const float* __restrict__ b1, float* __restrict__ ws) {
  __shared__ float sw1[80], sb1[8];
  __shared__ float sred[5][16];
  int tid = threadIdx.x;
  if (tid < 80) sw1[tid] = w1[tid];
  if (tid < 8)  sb1[tid] = b1[tid];
  __syncthreads();
  int l0 = blockIdx.x * 16;
  int n = tid;
  bool nv = n < N_NODES;
  float xx[26];
#pragma unroll
  for (int j = 0; j < 26; ++j) {
    int t = l0 + j;
    xx[j] = (nv && t < T_LEN) ? nfeat[(size_t)t * N_NODES + n] : 0.f;
  }
  float s[8], q[8];
#pragma unroll
  for (int c = 0; c < 8; ++c) { s[c] = 0.f; q[c] = 0.f; }
#pragma unroll
  for (int dl = 0; dl < 16; ++dl) {
    int l = l0 + dl;
    if (nv && l < L1) {
#pragma unroll
      for (int c = 0; c < 8; ++c) {
        float r = sb1[c];
#pragma unroll
        for (int k = 0; k < 10; ++k) r = fmaf(xx[dl + k], sw1[c * 10 + k], r);
        float z = fmaxf(r, 0.f);
        s[c] += z; q[c] += z * z;
      }
    }
  }
  int wv = tid >> 6, ln = tid & 63;
#pragma unroll
  for (int c = 0; c < 8; ++c) {
    float vs = s[c], vq = q[c];
    for (int o = 32; o; o >>= 1) { vs += __shfl_down(vs, o, 64); vq += __shfl_down(vq, o, 64); }
    if (ln == 0) { sred[wv][c] = vs; sred[wv][8 + c] = vq; }
  }
  __syncthreads();
  if (tid < 16) {
    float t = 0.f;
    for (int w = 0; w < 5; ++w) t += sred[w][tid];
    ws[WS_P1 + (size_t)blockIdx.x * 16 + tid] = t;
  }
}

// ================= K2: finalize bn1 =================
__global__ void dgl_k2_fin1(const float* __restrict__ g1, const float* __restrict__ b1,
                            float* __restrict__ ws) {
  __shared__ double sd[16];
  int tid = threadIdx.x;
  if (tid < 16) {
    double a = 0.0;
    for (int j = 0; j < 375; ++j) a += (double)ws[WS_P1 + (size_t)j * 16 + tid];
    sd[tid] = a;
  }
  __syncthreads();
  if (tid < 8) {
    double cnt = (double)N_NODES * (double)L1;
    double m = sd[tid] / cnt;
    double v = sd[tid + 8] / cnt - m * m;
    double inv = 1.0 / sqrt(v + 1e-5);
    ws[tid]     = (float)((double)g1[tid] * inv);
    ws[8 + tid] = (float)((double)b1[tid] - (double)g1[tid] * inv * m);
  }
}

// ================= K3: fused conv1+bn1 -> conv2 + relu -> a2 (PACKED) + stats =================
__global__ __launch_bounds__(256, 4) void dgl_k3_conv2(
    const float* __restrict__ nfeat, const float* __restrict__ w1, const float* __restrict__ b1,
    const float* __restrict__ w2, const float* __restrict__ b2, float* __restrict__ ws) {
  __shared__ float sx[26][64];
  __shared__ float sz[4][17][64];
  __shared__ float sw2[1280], sw1[80], sb1[8], sb2[16], ss1[8], st1[8];
  __shared__ float wpart[4][8];
  int tid = threadIdx.x;
  int lane = tid & 63, g = tid >> 6;
  int l0 = blockIdx.x * 8, n0 = blockIdx.y * 64;
  unsigned int* a2u = (unsigned int*)(ws + WS_A2);
  for (int i = tid; i < 1280; i += 256) sw2[i] = w2[i];
  if (tid < 80) sw1[tid] = w1[tid];
  if (tid < 8)  { sb1[tid] = b1[tid]; ss1[tid] = ws[tid]; st1[tid] = ws[8 + tid]; }
  if (tid < 16) sb2[tid] = b2[tid];
  for (int i = tid; i < 26 * 64; i += 256) {
    int j = i >> 6, l2 = i & 63;
    int t = l0 + j, nn = n0 + l2;
    sx[j][l2] = (t < T_LEN && nn < N_NODES) ? nfeat[(size_t)t * N_NODES + nn] : 0.f;
  }
  float acc[4][8];
#pragma unroll
  for (int qq = 0; qq < 4; ++qq)
#pragma unroll
    for (int dl = 0; dl < 8; ++dl) acc[qq][dl] = 0.f;
  __syncthreads();
#pragma unroll 1
  for (int p = 0; p < 2; ++p) {
    {
      int c = p * 4 + g;
#pragma unroll
      for (int lz = 0; lz < 17; ++lz) {
        float r = sb1[c];
#pragma unroll
        for (int k = 0; k < 10; ++k) r = fmaf(sx[lz + k][lane], sw1[c * 10 + k], r);
        sz[g][lz][lane] = fmaf(ss1[c], fmaxf(r, 0.f), st1[c]);
      }
    }
    __syncthreads();
#pragma unroll
    for (int c4 = 0; c4 < 4; ++c4) {
      int cin = p * 4 + c4;
      float zr[17];
#pragma unroll
      for (int t = 0; t < 17; ++t) zr[t] = sz[c4][t][lane];
#pragma unroll
      for (int k = 0; k < 10; ++k) {
#pragma unroll
        for (int qq = 0; qq < 4; ++qq) {
          float w = sw2[(g * 4 + qq) * 80 + cin * 10 + k];
#pragma unroll
          for (int dl = 0; dl < 8; ++dl) acc[qq][dl] = fmaf(zr[dl + k], w, acc[qq][dl]);
        }
      }
    }
    __syncthreads();
  }
  int n = n0 + lane;
  bool nv = n < N_NODES;
  float s4[4] = {0.f, 0.f, 0.f, 0.f}, q4[4] = {0.f, 0.f, 0.f, 0.f};
#pragma unroll
  for (int qq = 0; qq < 4; ++qq) {
    int c2 = g * 4 + qq;
#pragma unroll
    for (int dl = 0; dl < 8; ++dl) {
      int l = l0 + dl;
      float v = 0.f;
      if (nv && l < L2) v = fmaxf(acc[qq][dl] + sb2[c2], 0.f);
      if (l < L2) a2u[((size_t)c2 * L2 + l) * 320 + n] = pack2h(v);
      s4[qq] += v; q4[qq] += v * v;
    }
  }
#pragma unroll
  for (int qq = 0; qq < 4; ++qq) {
    float vs = s4[qq], vq = q4[qq];
    for (int o = 32; o; o >>= 1) { vs += __shfl_down(vs, o, 64); vq += __shfl_down(vq, o, 64); }
    if (lane == 0) { wpart[g][qq] = vs; wpart[g][4 + qq] = vq; }
  }
  __syncthreads();
  if (tid < 32) {
    int c2 = tid & 15; bool isq = tid >= 16;
    float v = wpart[c2 >> 2][(isq ? 4 : 0) + (c2 & 3)];
    ws[WS_P2 + ((size_t)blockIdx.y * gridDim.x + blockIdx.x) * 32 + tid] = v;
  }
}

// ================= K4: finalize bn2 =================
__global__ __launch_bounds__(512) void dgl_k4_fin2(const float* __restrict__ g2,
                                                   const float* __restrict__ b2,
                                                   float* __restrict__ ws) {
  __shared__ double dd[32][17];
  int tid = threadIdx.x;
  int v = tid >> 4, p = tid & 15;
  double a = 0.0;
  for (int j = p; j < 3740; j += 16) a += (double)ws[WS_P2 + (size_t)j * 32 + v];
  dd[v][p] = a;
  __syncthreads();
  if (tid < 32) {
    double s = 0.0;
    for (int pp = 0; pp < 16; ++pp) s += dd[tid][pp];
    dd[tid][16] = s;
  }
  __syncthreads();
  if (tid < 16) {
    double cnt = (double)N_NODES * (double)L2;
    double m = dd[tid][16] / cnt;
    double var = dd[tid + 16][16] / cnt - m * m;
    double inv = 1.0 / sqrt(var + 1e-5);
    ws[16 + tid] = (float)((double)g2[tid] * inv);
    ws[32 + tid] = (float)((double)b2[tid] - (double)g2[tid] * inv * m);
  }
}

// ================= K4b: colsum partials of fc_w + packed fcw copy =================
__global__ __launch_bounds__(384) void dgl_k4b_colsum(const float* __restrict__ fcw,
                                                      float* __restrict__ ws) {
  __shared__ float red[4][96];
  int b = blockIdx.x;                 // 0..255
  int c = b / LCPC, lc = b % LCPC;
  int clen = (lc == LCPC - 1) ? (L2 - CHL * (LCPC - 1)) : CHL;
  size_t fb = (size_t)c * L2 + (size_t)lc * CHL;
  unsigned int* bpu = (unsigned int*)(ws + WS_BP);
  int tid = threadIdx.x, rg = tid / 96, e = tid % 96;
  float a = 0.f;
  for (int r = rg; r < clen; r += 4) {
    float v = fcw[(fb + r) * 96 + e];
    bpu[(fb + r) * 96 + e] = pack2h(v);
    a += v;
  }
  red[rg][e] = a;
  __syncthreads();
  if (tid < 96) {
    float t = red[0][tid] + red[1][tid] + red[2][tid] + red[3][tid];
    ws[WS_CS + (size_t)b * 96 + tid] = t;
  }
}

// ================= K5 v11: one block per chunk, B-resident LDS, barrier-free K-loop =================
// 512 thr (8 waves), wave owns n-tiles {wv, wv+8, wv+16(<20)}; A direct global->frag.
__global__ __launch_bounds__(512, 2) void dgl_k5_fc(float* __restrict__ ws) {
  __shared__ unsigned int Bhl[96 * 192];   // [e][k-half], swizzled; 72 KB
  int tid = threadIdx.x;
  int ch = blockIdx.x;                     // 0..255
  int lc = ch & (LCPC - 1);
  int clen = (lc == LCPC - 1) ? (L2 - CHL * (LCPC - 1)) : CHL;   // 372 or 374
  size_t fb = (size_t)(ch >> 4) * L2 + (size_t)lc * CHL;
  const unsigned int* a2u = (const unsigned int*)(ws + WS_A2);
  const unsigned int* bpu = (const unsigned int*)(ws + WS_BP);
  int wv = tid >> 6, lane = tid & 63;
  int m = lane & 15, g = lane >> 4;
  bool hasC = (wv + 16) < 20;   // waves 0..3 own a third n-tile

  f32x4 acc1[3][6], acc2[3][6];
#pragma unroll
  for (int s = 0; s < 3; ++s)
#pragma unroll
    for (int t = 0; t < 6; ++t) {
      acc1[s][t] = (f32x4){0.f, 0.f, 0.f, 0.f};
      acc2[s][t] = (f32x4){0.f, 0.f, 0.f, 0.f};
    }

#pragma unroll 1
  for (int half = 0; half < 2; ++half) {
    int kb0 = half * 192;
    // ---- stage B half: rows kb0..kb0+191 into [e][k] LDS (zeros beyond clen) ----
#pragma unroll 1
    for (int it = 0; it < 9; ++it) {
      int idx = tid + it * 512;            // < 4608 = 192*24
      int r = idx % 192, eg = idx / 192;
      int rg = kb0 + r;
      uint4 v = (rg < clen) ? *(const uint4*)(bpu + (fb + rg) * 96 + eg * 4)
                            : make_uint4(0u, 0u, 0u, 0u);
      int e0 = eg * 4;
      Bhl[swzB(e0 + 0, r)] = v.x;
      Bhl[swzB(e0 + 1, r)] = v.y;
      Bhl[swzB(e0 + 2, r)] = v.z;
      Bhl[swzB(e0 + 3, r)] = v.w;
    }
    __syncthreads();
    // ---- 6 k32 steps, no barriers ----
#pragma unroll 1
    for (int ks = 0; ks < 6; ++ks) {
      int kbase = kb0 + ks * 32;
      int lim = clen - kbase;              // always >= 20
      U4H8 Ahi[3], Alo[3];
#pragma unroll
      for (int s = 0; s < 3; ++s) {
        unsigned int au[8];
        if (s < 2 || hasC) {
          int nt = wv + s * 8;
          const unsigned int* abase =
              a2u + ((size_t)(fb + kbase + 8 * g)) * 320 + nt * 16 + m;
          if (lim >= 32) {
#pragma unroll
            for (int j = 0; j < 8; ++j) au[j] = abase[(size_t)j * 320];
          } else {
#pragma unroll
            for (int j = 0; j < 8; ++j) {
              int kk2 = 8 * g + j;
              au[j] = (kk2 < lim) ? abase[(size_t)j * 320] : 0u;
            }
          }
        } else {
#pragma unroll
          for (int j = 0; j < 8; ++j) au[j] = 0u;
        }
        Ahi[s].u = make_uint4(
            (au[0] & 0xFFFFu) | (au[1] << 16), (au[2] & 0xFFFFu) | (au[3] << 16),
            (au[4] & 0xFFFFu) | (au[5] << 16), (au[6] & 0xFFFFu) | (au[7] << 16));
        Alo[s].u = make_uint4(
            (au[0] >> 16) | (au[1] & 0xFFFF0000u), (au[2] >> 16) | (au[3] & 0xFFFF0000u),
            (au[4] >> 16) | (au[5] & 0xFFFF0000u), (au[6] >> 16) | (au[7] & 0xFFFF0000u));
      }
#pragma unroll
      for (int t = 0; t < 6; ++t) {
        int e = 16 * t + m;
        int kl = ks * 32 + 8 * g;
        uint4 b0 = *(const uint4*)&Bhl[swzB(e, kl)];
        uint4 b1 = *(const uint4*)&Bhl[swzB(e, kl + 4)];
        U4H8 Bhi, Blo;
        Bhi.u = make_uint4(
            (b0.x & 0xFFFFu) | (b0.y << 16), (b0.z & 0xFFFFu) | (b0.w << 16),
            (b1.x & 0xFFFFu) | (b1.y << 16), (b1.z & 0xFFFFu) | (b1.w << 16));
        Blo.u = make_uint4(
            (b0.x >> 16) | (b0.y & 0xFFFF0000u), (b0.z >> 16) | (b0.w & 0xFFFF0000u),
            (b1.x >> 16) | (b1.y & 0xFFFF0000u), (b1.z >> 16) | (b1.w & 0xFFFF0000u));
        acc1[0][t] = __builtin_amdgcn_mfma_f32_16x16x32_f16(Ahi[0].h, Bhi.h, acc1[0][t], 0, 0, 0);
        acc2[0][t] = __builtin_amdgcn_mfma_f32_16x16x32_f16(Ahi[0].h, Blo.h, acc2[0][t], 0, 0, 0);
        acc2[0][t] = __builtin_amdgcn_mfma_f32_16x16x32_f16(Alo[0].h, Bhi.h, acc2[0][t], 0, 0, 0);
        acc1[1][t] = __builtin_amdgcn_mfma_f32_16x16x32_f16(Ahi[1].h, Bhi.h, acc1[1][t], 0, 0, 0);
        acc2[1][t] = __builtin_amdgcn_mfma_f32_16x16x32_f16(Ahi[1].h, Blo.h, acc2[1][t], 0, 0, 0);
        acc2[1][t] = __builtin_amdgcn_mfma_f32_16x16x32_f16(Alo[1].h, Bhi.h, acc2[1][t], 0, 0, 0);
        if (hasC) {
          acc1[2][t] = __builtin_amdgcn_mfma_f32_16x16x32_f16(Ahi[2].h, Bhi.h, acc1[2][t], 0, 0, 0);
          acc2[2][t] = __builtin_amdgcn_mfma_f32_16x16x32_f16(Ahi[2].h, Blo.h, acc2[2][t], 0, 0, 0);
          acc2[2][t] = __builtin_amdgcn_mfma_f32_16x16x32_f16(Alo[2].h, Bhi.h, acc2[2][t], 0, 0, 0);
        }
      }
    }
    __syncthreads();   // protect Bhl before restage
  }
  // ---- epilogue: e = 16t+m, n = nt*16 + 4g + r ----
  float* fp = ws + WS_FP;
#pragma unroll
  for (int s = 0; s < 3; ++s) {
    if (s < 2 || hasC) {
      int nt = wv + s * 8;
#pragma unroll
      for (int t = 0; t < 6; ++t) {
        int e = 16 * t + m;
        float4 o;
        o.x = acc1[s][t][0] + acc2[s][t][0] * (1.0f / 2048.0f);
        o.y = acc1[s][t][1] + acc2[s][t][1] * (1.0f / 2048.0f);
        o.z = acc1[s][t][2] + acc2[s][t][2] * (1.0f / 2048.0f);
        o.w = acc1[s][t][3] + acc2[s][t][3] * (1.0f / 2048.0f);
        *(float4*)(fp + ((size_t)ch * 96 + e) * 320 + nt * 16 + 4 * g) = o;
      }
    }
  }
}

// ================= K6: fp64 combine (s2*P + t2*colsum + fcb) + relu + bn3 =================
__global__ __launch_bounds__(320) void dgl_k6_bn3(const float* __restrict__ fcb,
                                                  const float* __restrict__ g3,
                                                  const float* __restrict__ b3,
                                                  float* __restrict__ ws) {
  int e = blockIdx.x, tid = threadIdx.x;
  __shared__ double s2d[16], csd[16];
  __shared__ double rs[5], rq[5];
  __shared__ float mb[2];
  if (tid < 16) {
    s2d[tid] = (double)ws[16 + tid];
    double a = 0.0;
#pragma unroll
    for (int lc = 0; lc < LCPC; ++lc)
      a += (double)ws[WS_CS + (size_t)(tid * LCPC + lc) * 96 + e];
    csd[tid] = a * (double)ws[32 + tid];   // t2[c] * colsum_c[e]
  }
  __syncthreads();
  const float* fp = ws + WS_FP;
  double a = 0.0;
#pragma unroll 2
  for (int c = 0; c < 16; ++c) {
    double pc = 0.0;
    for (int lc = 0; lc < LCPC; ++lc) {
      int ch = c * LCPC + lc;
      pc += (double)fp[((size_t)ch * 96 + e) * 320 + tid];
    }
    a += s2d[c] * pc;
  }
  double cst = 0.0;
#pragma unroll
  for (int c = 0; c < 16; ++c) cst += csd[c];
  float x = fmaxf((float)(a + cst) + fcb[e], 0.f);
  if (tid >= N_NODES) x = 0.f;
  double s = (double)x, q = (double)x * (double)x;
  int wv = tid >> 6, ln = tid & 63;
  for (int o = 32; o; o >>= 1) { s += __shfl_down(s, o, 64); q += __shfl_down(q, o, 64); }
  if (ln == 0) { rs[wv] = s; rq[wv] = q; }
  __syncthreads();
  if (tid == 0) {
    double S = 0.0, Q = 0.0;
    for (int w = 0; w < 5; ++w) { S += rs[w]; Q += rq[w]; }
    double m = S / (double)N_NODES;
    double var = Q / (double)N_NODES - m * m;
    mb[0] = (float)m; mb[1] = (float)(1.0 / sqrt(var + 1e-5));
  }
  __syncthreads();
  if (tid < N_NODES)
    ws[WS_NF + (size_t)tid * 96 + e] = g3[e] * (x - mb[0]) * mb[1] + b3[e];
}

// ================= K7: s_proj / r_proj =================
__global__ __launch_bounds__(192) void dgl_k7_proj(const float* __restrict__ fow,
                                                   float* __restrict__ ws) {
  __shared__ float sh[96];
  int nI = blockIdx.x, tid = threadIdx.x;
  if (tid < 96) sh[tid] = ws[WS_NF + (size_t)nI * 96 + tid];
  __syncthreads();
  int col = tid % 96, half = tid / 96;
  float a = 0.f;
#pragma unroll 8
  for (int d = 0; d < 96; ++d) a = fmaf(sh[d], fow[(size_t)(half * 96 + d) * 96 + col], a);
  ws[(half ? WS_RP : WS_SP) + (size_t)nI * 96 + col] = a;
}

// ================= K8: edge relu + logits + gumbel + hard argmax -> adj =================
__global__ __launch_bounds__(256) void dgl_k8_edge(const float* __restrict__ fob,
                                                   const float* __restrict__ fcatw,
                                                   const float* __restrict__ fcatb,
                                                   const float* __restrict__ unif,
                                                   const float* __restrict__ ws,
                                                   float* __restrict__ out) {
  __shared__ float rp[16][100], sp[16][100], bb[96], wa[96], wb[96];
  int tid = threadIdx.x;
  int i0 = blockIdx.y * 16, j0 = blockIdx.x * 16;
  for (int idx = tid; idx < 16 * 96; idx += 256) {
    int r = idx / 96, e = idx % 96;
    int ii = i0 + r, jj = j0 + r;
    rp[r][e] = (ii < N_NODES) ? ws[WS_RP + (size_t)ii * 96 + e] : 0.f;
    sp[r][e] = (jj < N_NODES) ? ws[WS_SP + (size_t)jj * 96 + e] : 0.f;
  }
  if (tid < 96) { bb[tid] = fob[tid]; wa[tid] = fcatw[2 * tid]; wb[tid] = fcatw[2 * tid + 1]; }
  __syncthreads();
  int il = tid >> 4, jl = tid & 15;
  int i = i0 + il, j = j0 + jl;
  float a0 = 0.f, a1 = 0.f;
#pragma unroll 4
  for (int e = 0; e < 96; ++e) {
    float ef = fmaxf(rp[il][e] + sp[jl][e] + bb[e], 0.f);
    a0 = fmaf(ef, wa[e], a0);
    a1 = fmaf(ef, wb[e], a1);
  }
  if (i < N_NODES && j < N_NODES) {
    size_t ue = ((size_t)i * N_NODES + j) * 2;
    float g0 = -logf(-logf(unif[ue] + 1e-20f) + 1e-20f);
    float g1 = -logf(-logf(unif[ue + 1] + 1e-20f) + 1e-20f);
    float z0 = a0 + fcatb[0] + g0;
    float z1 = a1 + fcatb[1] + g1;
    out[(size_t)i * N_NODES + j] = (i == j) ? 0.f : ((z0 >= z1) ? 1.f : 0.f);
  }
}

extern "C" void kernel_launch(void* const* d_in, const int* in_sizes, int n_in,
                              void* d_out, int out_size, void* d_ws, size_t ws_size,
                              hipStream_t stream) {
  const float* nfeat = (const float*)d_in[1];
  const float* w1    = (const float*)d_in[2];
  const float* b1    = (const float*)d_in[3];
  const float* w2    = (const float*)d_in[4];
  const float* b2    = (const float*)d_in[5];
  const float* g1    = (const float*)d_in[6];
  const float* bb1   = (const float*)d_in[7];
  const float* g2    = (const float*)d_in[8];
  const float* bb2   = (const float*)d_in[9];
  const float* g3    = (const float*)d_in[10];
  const float* bb3   = (const float*)d_in[11];
  const float* fcw   = (const float*)d_in[12];
  const float* fcb   = (const float*)d_in[13];
  const float* fow   = (const float*)d_in[14];
  const float* fob   = (const float*)d_in[15];
  const float* fcatw = (const float*)d_in[16];
  const float* fcatb = (const float*)d_in[17];
  const float* unif  = (const float*)d_in[18];
  float* ws  = (float*)d_ws;
  float* out = (float*)d_out;

  dgl_k4b_colsum<<<dim3(K5CH), dim3(384), 0, stream>>>(fcw, ws);
  dgl_k1_conv1_stats<<<dim3(375), dim3(320), 0, stream>>>(nfeat, w1, b1, ws);
  dgl_k2_fin1<<<dim3(1), dim3(64), 0, stream>>>(g1, bb1, ws);
  dgl_k3_conv2<<<dim3(748, 5), dim3(256), 0, stream>>>(nfeat, w1, b1, w2, b2, ws);
  dgl_k4_fin2<<<dim3(1), dim3(512), 0, stream>>>(g2, bb2, ws);
  dgl_k5_fc<<<dim3(K5CH), dim3(512), 0, stream>>>(ws);
  dgl_k6_bn3<<<dim3(96), dim3(320), 0, stream>>>(fcb, g3, bb3, ws);
  dgl_k7_proj<<<dim3(307), dim3(192), 0, stream>>>(fow, ws);
  dgl_k8_edge<<<dim3(20, 20), dim3(256), 0, stream>>>(fob, fcatw, fcatb, unif, ws, out);
}

// Round 12
// 236.738 us; speedup vs baseline: 1.5786x; 1.1925x over previous
//
#include <hip/hip_runtime.h>
#include <hip/hip_fp16.h>

#define N_NODES 307
#define T_LEN   6000
#define L1      5991
#define L2      5982
#define ED      96
#define FDIM    95712
#define NCH2    16
#define LCPC    16                  // l-chunks per channel
#define CHL     374                 // rows per l-chunk (last = 372)
#define K5CH    (NCH2 * LCPC)       // 256 K-chunks, channel-pure
#define K3LB    94                  // K3 l-blocks (64 outputs each)
#define K3NB    20                  // K3 n-blocks (16 each)
#define K3BLKS  (K3LB * K3NB)       // 1880

// ---- workspace layout (float/u32 offsets) ---- (identical to R10/R11)
static const size_t WS_P1 = 256;                    // conv1 stat partials: 375*16
static const size_t WS_P2 = 8192;                   // conv2 stat partials: 1880*32
static const size_t WS_CS = 131072;                 // colsum partials: 256*96
static const size_t WS_NF = 155648;                 // node_feat 307*96
static const size_t WS_SP = 188416;                 // s_proj
static const size_t WS_RP = 221184;                 // r_proj
static const size_t WS_A2 = 262144;                 // a2 PACKED u32: 95712*320
static const size_t WS_FP = 262144 + 30627840ull;   // fc partials: 256*96*320
static const size_t WS_BP = 30889984ull + 7864320ull; // packed fcw u32: 95712*96
// total ~= 192.3 MB

typedef _Float16 half8 __attribute__((ext_vector_type(8)));
typedef float f32x4 __attribute__((ext_vector_type(4)));

union U4H8 { uint4 u; half8 h; };

// pack fp32 -> (f16 hi | f16 lo<<16), x ~= hi + lo/2048
__device__ __forceinline__ unsigned int pack2h(float x) {
  __half h = __float2half(x);
  float r = (x - __half2float(h)) * 2048.0f;
  __half l = __float2half(r);
  return (unsigned int)__half_as_ushort(h) | ((unsigned int)__half_as_ushort(l) << 16);
}

__device__ __forceinline__ void unpackU4(const uint4& a0, const uint4& a1,
                                         U4H8& hi, U4H8& lo) {
  hi.u = make_uint4((a0.x & 0xFFFFu) | (a0.y << 16), (a0.z & 0xFFFFu) | (a0.w << 16),
                    (a1.x & 0xFFFFu) | (a1.y << 16), (a1.z & 0xFFFFu) | (a1.w << 16));
  lo.u = make_uint4((a0.x >> 16) | (a0.y & 0xFFFF0000u), (a0.z >> 16) | (a0.w & 0xFFFF0000u),
                    (a1.x >> 16) | (a1.y & 0xFFFF0000u), (a1.z >> 16) | (a1.w & 0xFFFF0000u));
}

// B-LDS swizzle for K5: [e][k] rows of 192 u32, 16B-chunk XOR by e&7.
__device__ __forceinline__ int swzB(int e, int k) {
  return e * 192 + (((k >> 2) ^ (e & 7)) << 2) + (k & 3);
}

// ================= K1: conv1 + relu, channel stats only =================
__global__ __launch_bounds__(320) void dgl_k1_conv1_stats(
    const float* __restrict__ nfeat, const float* __restrict__ w1,
    const float* __restrict__ b1, float* __restrict__ ws) {
  __shared__ float sw1[80], sb1[8];
  __shared__ float sred[5][16];
  int tid = threadIdx.x;
  if (tid < 80) sw1[tid] = w1[tid];
  if (tid < 8)  sb1[tid] = b1[tid];
  __syncthreads();
  int l0 = blockIdx.x * 16;
  int n = tid;
  bool nv = n < N_NODES;
  float xx[26];
#pragma unroll
  for (int j = 0; j < 26; ++j) {
    int t = l0 + j;
    xx[j] = (nv && t < T_LEN) ? nfeat[(size_t)t * N_NODES + n] : 0.f;
  }
  float s[8], q[8];
#pragma unroll
  for (int c = 0; c < 8; ++c) { s[c] = 0.f; q[c] = 0.f; }
#pragma unroll
  for (int dl = 0; dl < 16; ++dl) {
    int l = l0 + dl;
    if (nv && l < L1) {
#pragma unroll
      for (int c = 0; c < 8; ++c) {
        float r = sb1[c];
#pragma unroll
        for (int k = 0; k < 10; ++k) r = fmaf(xx[dl + k], sw1[c * 10 + k], r);
        float z = fmaxf(r, 0.f);
        s[c] += z; q[c] += z * z;
      }
    }
  }
  int wv = tid >> 6, ln = tid & 63;
#pragma unroll
  for (int c = 0; c < 8; ++c) {
    float vs = s[c], vq = q[c];
    for (int o = 32; o; o >>= 1) { vs += __shfl_down(vs, o, 64); vq += __shfl_down(vq, o, 64); }
    if (ln == 0) { sred[wv][c] = vs; sred[wv][8 + c] = vq; }
  }
  __syncthreads();
  if (tid < 16) {
    float t = 0.f;
    for (int w = 0; w < 5; ++w) t += sred[w][tid];
    ws[WS_P1 + (size_t)blockIdx.x * 16 + tid] = t;
  }
}

// ================= K2: finalize bn1 =================
__global__ void dgl_k2_fin1(const float* __restrict__ g1, const float* __restrict__ b1,
                            float* __restrict__ ws) {
  __shared__ double sd[16];
  int tid = threadIdx.x;
  if (tid < 16) {
    double a = 0.0;
    for (int j = 0; j < 375; ++j) a += (double)ws[WS_P1 + (size_t)j * 16 + tid];
    sd[tid] = a;
  }
  __syncthreads();
  if (tid < 8) {
    double cnt = (double)N_NODES * (double)L1;
    double m = sd[tid] / cnt;
    double v = sd[tid + 8] / cnt - m * m;
    double inv = 1.0 / sqrt(v + 1e-5);
    ws[tid]     = (float)((double)g1[tid] * inv);
    ws[8 + tid] = (float)((double)b1[tid] - (double)g1[tid] * inv * m);
  }
}

// ================= K3 (MFMA): conv1+bn1 -> z1 packed LDS -> conv2 via split-f16 MFMA =================
// kk = k*8 + cin (pad 96). A = w2p[c2][kk] (zeros kk>=80). B[n][kk] = z1[cin][l+k][n]
// from z1p[pos][n'][cin] (n' = n ^ (pos&15)): lane(m,g) Kstep s reads 8 contiguous u32.
// D: row 4g+r -> c2, col m -> n. Output packed into a2u + bn2 stats.
__global__ __launch_bounds__(256) void dgl_k3_conv2(
    const float* __restrict__ nfeat, const float* __restrict__ w1, const float* __restrict__ b1,
    const float* __restrict__ w2, const float* __restrict__ b2, float* __restrict__ ws) {
  __shared__ __align__(16) unsigned int z1p[75 * 128];  // [lp][n'][cin], 38.4 KB
  __shared__ __align__(16) unsigned int w2p[16 * 96];   // [c2][kk]
  __shared__ float sx[84 * 16];                         // [t-local][n]
  __shared__ float sw1[80], sb1[8], ss1[8], st1[8], sb2v[16];
  __shared__ float wps[4][4][4], wpq[4][4][4];
  int tid = threadIdx.x;
  int l0b = blockIdx.x * 64, n0 = blockIdx.y * 16;
  unsigned int* a2u = (unsigned int*)(ws + WS_A2);

  if (tid < 80) sw1[tid] = w1[tid];
  if (tid < 8)  { sb1[tid] = b1[tid]; ss1[tid] = ws[tid]; st1[tid] = ws[8 + tid]; }
  if (tid < 16) sb2v[tid] = b2[tid];
  for (int i = tid; i < 16 * 96; i += 256) {
    int c2 = i / 96, kk = i % 96;
    float v = (kk < 80) ? w2[c2 * 80 + (kk & 7) * 10 + (kk >> 3)] : 0.f;
    w2p[i] = pack2h(v);
  }
  for (int i = tid; i < 84 * 16; i += 256) {
    int tl = i >> 4, nn = i & 15;
    int t = l0b + tl, n = n0 + nn;
    sx[i] = (t < T_LEN && n < N_NODES) ? nfeat[(size_t)t * N_NODES + n] : 0.f;
  }
  __syncthreads();
  // z1 build: 75 pos x 16 n x 8 cin
  for (int i = tid; i < 9600; i += 256) {
    int lp = i >> 7, rem = i & 127;
    int n = rem >> 3, cin = rem & 7;
    float r = sb1[cin];
#pragma unroll
    for (int k = 0; k < 10; ++k) r = fmaf(sx[(lp + k) * 16 + n], sw1[cin * 10 + k], r);
    float z = fmaf(ss1[cin], fmaxf(r, 0.f), st1[cin]);
    z1p[lp * 128 + ((n ^ (lp & 15)) << 3) + cin] = pack2h(z);
  }
  __syncthreads();

  int wv = tid >> 6, lane = tid & 63;
  int m = lane & 15, g = lane >> 4;
  U4H8 Ahi[3], Alo[3];
#pragma unroll
  for (int s = 0; s < 3; ++s) {
    const unsigned int* ap = &w2p[m * 96 + 32 * s + 8 * g];
    uint4 a0 = *(const uint4*)ap;
    uint4 a1 = *(const uint4*)(ap + 4);
    unpackU4(a0, a1, Ahi[s], Alo[s]);
  }
  float sv[4] = {0.f, 0.f, 0.f, 0.f}, qv[4] = {0.f, 0.f, 0.f, 0.f};
  int nglob = n0 + m;
  bool nok = nglob < N_NODES;
#pragma unroll 1
  for (int li = 0; li < 16; ++li) {
    int ll = 16 * wv + li;
    int lg = l0b + ll;
    f32x4 ac1 = (f32x4){0.f, 0.f, 0.f, 0.f};
    f32x4 ac2 = (f32x4){0.f, 0.f, 0.f, 0.f};
#pragma unroll
    for (int s = 0; s < 3; ++s) {
      int lp = ll + 4 * s + g;
      const unsigned int* bp = &z1p[lp * 128 + ((m ^ (lp & 15)) << 3)];
      uint4 b0 = *(const uint4*)bp;
      uint4 b1 = *(const uint4*)(bp + 4);
      U4H8 Bhi, Blo;
      unpackU4(b0, b1, Bhi, Blo);
      ac1 = __builtin_amdgcn_mfma_f32_16x16x32_f16(Ahi[s].h, Bhi.h, ac1, 0, 0, 0);
      ac2 = __builtin_amdgcn_mfma_f32_16x16x32_f16(Ahi[s].h, Blo.h, ac2, 0, 0, 0);
      ac2 = __builtin_amdgcn_mfma_f32_16x16x32_f16(Alo[s].h, Bhi.h, ac2, 0, 0, 0);
    }
    if (lg < L2) {
#pragma unroll
      for (int r = 0; r < 4; ++r) {
        float v = ac1[r] + ac2[r] * (1.0f / 2048.0f) + sb2v[4 * g + r];
        v = fmaxf(v, 0.f);
        if (!nok) v = 0.f;
        sv[r] += v; qv[r] += v * v;
        a2u[((size_t)(4 * g + r) * L2 + lg) * 320 + nglob] = pack2h(v);
      }
    }
  }
  // stats: reduce over the 16 m-lanes of each g-group (deterministic tree)
#pragma unroll
  for (int r = 0; r < 4; ++r) {
    for (int o = 1; o < 16; o <<= 1) {
      sv[r] += __shfl_xor(sv[r], o, 64);
      qv[r] += __shfl_xor(qv[r], o, 64);
    }
  }
  if (m == 0) {
#pragma unroll
    for (int r = 0; r < 4; ++r) { wps[wv][g][r] = sv[r]; wpq[wv][g][r] = qv[r]; }
  }
  __syncthreads();
  if (tid < 32) {
    int c2 = tid & 15; bool isq = tid >= 16;
    int gg = c2 >> 2, rr = c2 & 3;
    float t = 0.f;
    for (int w = 0; w < 4; ++w) t += isq ? wpq[w][gg][rr] : wps[w][gg][rr];
    ws[WS_P2 + ((size_t)blockIdx.y * gridDim.x + blockIdx.x) * 32 + tid] = t;
  }
}

// ================= K4: finalize bn2 =================
__global__ __launch_bounds__(512) void dgl_k4_fin2(const float* __restrict__ g2,
                                                   const float* __restrict__ b2,
                                                   float* __restrict__ ws) {
  __shared__ double dd[32][17];
  int tid = threadIdx.x;
  int v = tid >> 4, p = tid & 15;
  double a = 0.0;
  for (int j = p; j < K3BLKS; j += 16) a += (double)ws[WS_P2 + (size_t)j * 32 + v];
  dd[v][p] = a;
  __syncthreads();
  if (tid < 32) {
    double s = 0.0;
    for (int pp = 0; pp < 16; ++pp) s += dd[tid][pp];
    dd[tid][16] = s;
  }
  __syncthreads();
  if (tid < 16) {
    double cnt = (double)N_NODES * (double)L2;
    double m = dd[tid][16] / cnt;
    double var = dd[tid + 16][16] / cnt - m * m;
    double inv = 1.0 / sqrt(var + 1e-5);
    ws[16 + tid] = (float)((double)g2[tid] * inv);
    ws[32 + tid] = (float)((double)b2[tid] - (double)g2[tid] * inv * m);
  }
}

// ================= K4b: colsum partials of fc_w + packed fcw copy =================
__global__ __launch_bounds__(384) void dgl_k4b_colsum(const float* __restrict__ fcw,
                                                      float* __restrict__ ws) {
  __shared__ float red[4][96];
  int b = blockIdx.x;                 // 0..255
  int c = b / LCPC, lc = b % LCPC;
  int clen = (lc == LCPC - 1) ? (L2 - CHL * (LCPC - 1)) : CHL;
  size_t fb = (size_t)c * L2 + (size_t)lc * CHL;
  unsigned int* bpu = (unsigned int*)(ws + WS_BP);
  int tid = threadIdx.x, rg = tid / 96, e = tid % 96;
  float a = 0.f;
  for (int r = rg; r < clen; r += 4) {
    float v = fcw[(fb + r) * 96 + e];
    bpu[(fb + r) * 96 + e] = pack2h(v);
    a += v;
  }
  red[rg][e] = a;
  __syncthreads();
  if (tid < 96) {
    float t = red[0][tid] + red[1][tid] + red[2][tid] + red[3][tid];
    ws[WS_CS + (size_t)b * 96 + tid] = t;
  }
}

// ================= K5 v11: one block per chunk, B-resident LDS, barrier-free K-loop =================
__global__ __launch_bounds__(512, 2) void dgl_k5_fc(float* __restrict__ ws) {
  __shared__ unsigned int Bhl[96 * 192];   // [e][k-half], swizzled; 72 KB
  int tid = threadIdx.x;
  int ch = blockIdx.x;                     // 0..255
  int lc = ch & (LCPC - 1);
  int clen = (lc == LCPC - 1) ? (L2 - CHL * (LCPC - 1)) : CHL;   // 372 or 374
  size_t fb = (size_t)(ch >> 4) * L2 + (size_t)lc * CHL;
  const unsigned int* a2u = (const unsigned int*)(ws + WS_A2);
  const unsigned int* bpu = (const unsigned int*)(ws + WS_BP);
  int wv = tid >> 6, lane = tid & 63;
  int m = lane & 15, g = lane >> 4;
  bool hasC = (wv + 16) < 20;

  f32x4 acc1[3][6], acc2[3][6];
#pragma unroll
  for (int s = 0; s < 3; ++s)
#pragma unroll
    for (int t = 0; t < 6; ++t) {
      acc1[s][t] = (f32x4){0.f, 0.f, 0.f, 0.f};
      acc2[s][t] = (f32x4){0.f, 0.f, 0.f, 0.f};
    }

#pragma unroll 1
  for (int half = 0; half < 2; ++half) {
    int kb0 = half * 192;
#pragma unroll 1
    for (int it = 0; it < 9; ++it) {
      int idx = tid + it * 512;
      int r = idx % 192, eg = idx / 192;
      int rg = kb0 + r;
      uint4 v = (rg < clen) ? *(const uint4*)(bpu + (fb + rg) * 96 + eg * 4)
                            : make_uint4(0u, 0u, 0u, 0u);
      int e0 = eg * 4;
      Bhl[swzB(e0 + 0, r)] = v.x;
      Bhl[swzB(e0 + 1, r)] = v.y;
      Bhl[swzB(e0 + 2, r)] = v.z;
      Bhl[swzB(e0 + 3, r)] = v.w;
    }
    __syncthreads();
#pragma unroll 1
    for (int ks = 0; ks < 6; ++ks) {
      int kbase = kb0 + ks * 32;
      int lim = clen - kbase;
      U4H8 Ahi[3], Alo[3];
#pragma unroll
      for (int s = 0; s < 3; ++s) {
        unsigned int au[8];
        if (s < 2 || hasC) {
          int nt = wv + s * 8;
          const unsigned int* abase =
              a2u + ((size_t)(fb + kbase + 8 * g)) * 320 + nt * 16 + m;
          if (lim >= 32) {
#pragma unroll
            for (int j = 0; j < 8; ++j) au[j] = abase[(size_t)j * 320];
          } else {
#pragma unroll
            for (int j = 0; j < 8; ++j) {
              int kk2 = 8 * g + j;
              au[j] = (kk2 < lim) ? abase[(size_t)j * 320] : 0u;
            }
          }
        } else {
#pragma unroll
          for (int j = 0; j < 8; ++j) au[j] = 0u;
        }
        uint4 a0 = make_uint4(au[0], au[1], au[2], au[3]);
        uint4 a1 = make_uint4(au[4], au[5], au[6], au[7]);
        unpackU4(a0, a1, Ahi[s], Alo[s]);
      }
#pragma unroll
      for (int t = 0; t < 6; ++t) {
        int e = 16 * t + m;
        int kl = ks * 32 + 8 * g;
        uint4 b0 = *(const uint4*)&Bhl[swzB(e, kl)];
        uint4 b1 = *(const uint4*)&Bhl[swzB(e, kl + 4)];
        U4H8 Bhi, Blo;
        unpackU4(b0, b1, Bhi, Blo);
        acc1[0][t] = __builtin_amdgcn_mfma_f32_16x16x32_f16(Ahi[0].h, Bhi.h, acc1[0][t], 0, 0, 0);
        acc2[0][t] = __builtin_amdgcn_mfma_f32_16x16x32_f16(Ahi[0].h, Blo.h, acc2[0][t], 0, 0, 0);
        acc2[0][t] = __builtin_amdgcn_mfma_f32_16x16x32_f16(Alo[0].h, Bhi.h, acc2[0][t], 0, 0, 0);
        acc1[1][t] = __builtin_amdgcn_mfma_f32_16x16x32_f16(Ahi[1].h, Bhi.h, acc1[1][t], 0, 0, 0);
        acc2[1][t] = __builtin_amdgcn_mfma_f32_16x16x32_f16(Ahi[1].h, Blo.h, acc2[1][t], 0, 0, 0);
        acc2[1][t] = __builtin_amdgcn_mfma_f32_16x16x32_f16(Alo[1].h, Bhi.h, acc2[1][t], 0, 0, 0);
        if (hasC) {
          acc1[2][t] = __builtin_amdgcn_mfma_f32_16x16x32_f16(Ahi[2].h, Bhi.h, acc1[2][t], 0, 0, 0);
          acc2[2][t] = __builtin_amdgcn_mfma_f32_16x16x32_f16(Ahi[2].h, Blo.h, acc2[2][t], 0, 0, 0);
          acc2[2][t] = __builtin_amdgcn_mfma_f32_16x16x32_f16(Alo[2].h, Bhi.h, acc2[2][t], 0, 0, 0);
        }
      }
    }
    __syncthreads();
  }
  float* fp = ws + WS_FP;
#pragma unroll
  for (int s = 0; s < 3; ++s) {
    if (s < 2 || hasC) {
      int nt = wv + s * 8;
#pragma unroll
      for (int t = 0; t < 6; ++t) {
        int e = 16 * t + m;
        float4 o;
        o.x = acc1[s][t][0] + acc2[s][t][0] * (1.0f / 2048.0f);
        o.y = acc1[s][t][1] + acc2[s][t][1] * (1.0f / 2048.0f);
        o.z = acc1[s][t][2] + acc2[s][t][2] * (1.0f / 2048.0f);
        o.w = acc1[s][t][3] + acc2[s][t][3] * (1.0f / 2048.0f);
        *(float4*)(fp + ((size_t)ch * 96 + e) * 320 + nt * 16 + 4 * g) = o;
      }
    }
  }
}

// ================= K6: fp64 combine (s2*P + t2*colsum + fcb) + relu + bn3 =================
__global__ __launch_bounds__(320) void dgl_k6_bn3(const float* __restrict__ fcb,
                                                  const float* __restrict__ g3,
                                                  const float* __restrict__ b3,
                                                  float* __restrict__ ws) {
  int e = blockIdx.x, tid = threadIdx.x;
  __shared__ double s2d[16], csd[16];
  __shared__ double rs[5], rq[5];
  __shared__ float mb[2];
  if (tid < 16) {
    s2d[tid] = (double)ws[16 + tid];
    double a = 0.0;
#pragma unroll
    for (int lc = 0; lc < LCPC; ++lc)
      a += (double)ws[WS_CS + (size_t)(tid * LCPC + lc) * 96 + e];
    csd[tid] = a * (double)ws[32 + tid];
  }
  __syncthreads();
  const float* fp = ws + WS_FP;
  double a = 0.0;
#pragma unroll 2
  for (int c = 0; c < 16; ++c) {
    double pc = 0.0;
    for (int lc = 0; lc < LCPC; ++lc) {
      int ch = c * LCPC + lc;
      pc += (double)fp[((size_t)ch * 96 + e) * 320 + tid];
    }
    a += s2d[c] * pc;
  }
  double cst = 0.0;
#pragma unroll
  for (int c = 0; c < 16; ++c) cst += csd[c];
  float x = fmaxf((float)(a + cst) + fcb[e], 0.f);
  if (tid >= N_NODES) x = 0.f;
  double s = (double)x, q = (double)x * (double)x;
  int wv = tid >> 6, ln = tid & 63;
  for (int o = 32; o; o >>= 1) { s += __shfl_down(s, o, 64); q += __shfl_down(q, o, 64); }
  if (ln == 0) { rs[wv] = s; rq[wv] = q; }
  __syncthreads();
  if (tid == 0) {
    double S = 0.0, Q = 0.0;
    for (int w = 0; w < 5; ++w) { S += rs[w]; Q += rq[w]; }
    double m = S / (double)N_NODES;
    double var = Q / (double)N_NODES - m * m;
    mb[0] = (float)m; mb[1] = (float)(1.0 / sqrt(var + 1e-5));
  }
  __syncthreads();
  if (tid < N_NODES)
    ws[WS_NF + (size_t)tid * 96 + e] = g3[e] * (x - mb[0]) * mb[1] + b3[e];
}

// ================= K7: s_proj / r_proj =================
__global__ __launch_bounds__(192) void dgl_k7_proj(const float* __restrict__ fow,
                                                   float* __restrict__ ws) {
  __shared__ float sh[96];
  int nI = blockIdx.x, tid = threadIdx.x;
  if (tid < 96) sh[tid] = ws[WS_NF + (size_t)nI * 96 + tid];
  __syncthreads();
  int col = tid % 96, half = tid / 96;
  float a = 0.f;
#pragma unroll 8
  for (int d = 0; d < 96; ++d) a = fmaf(sh[d], fow[(size_t)(half * 96 + d) * 96 + col], a);
  ws[(half ? WS_RP : WS_SP) + (size_t)nI * 96 + col] = a;
}

// ================= K8: edge relu + logits + gumbel + hard argmax -> adj =================
__global__ __launch_bounds__(256) void dgl_k8_edge(const float* __restrict__ fob,
                                                   const float* __restrict__ fcatw,
                                                   const float* __restrict__ fcatb,
                                                   const float* __restrict__ unif,
                                                   const float* __restrict__ ws,
                                                   float* __restrict__ out) {
  __shared__ float rp[16][100], sp[16][100], bb[96], wa[96], wb[96];
  int tid = threadIdx.x;
  int i0 = blockIdx.y * 16, j0 = blockIdx.x * 16;
  for (int idx = tid; idx < 16 * 96; idx += 256) {
    int r = idx / 96, e = idx % 96;
    int ii = i0 + r, jj = j0 + r;
    rp[r][e] = (ii < N_NODES) ? ws[WS_RP + (size_t)ii * 96 + e] : 0.f;
    sp[r][e] = (jj < N_NODES) ? ws[WS_SP + (size_t)jj * 96 + e] : 0.f;
  }
  if (tid < 96) { bb[tid] = fob[tid]; wa[tid] = fcatw[2 * tid]; wb[tid] = fcatw[2 * tid + 1]; }
  __syncthreads();
  int il = tid >> 4, jl = tid & 15;
  int i = i0 + il, j = j0 + jl;
  float a0 = 0.f, a1 = 0.f;
#pragma unroll 4
  for (int e = 0; e < 96; ++e) {
    float ef = fmaxf(rp[il][e] + sp[jl][e] + bb[e], 0.f);
    a0 = fmaf(ef, wa[e], a0);
    a1 = fmaf(ef, wb[e], a1);
  }
  if (i < N_NODES && j < N_NODES) {
    size_t ue = ((size_t)i * N_NODES + j) * 2;
    float g0 = -logf(-logf(unif[ue] + 1e-20f) + 1e-20f);
    float g1 = -logf(-logf(unif[ue + 1] + 1e-20f) + 1e-20f);
    float z0 = a0 + fcatb[0] + g0;
    float z1 = a1 + fcatb[1] + g1;
    out[(size_t)i * N_NODES + j] = (i == j) ? 0.f : ((z0 >= z1) ? 1.f : 0.f);
  }
}

extern "C" void kernel_launch(void* const* d_in, const int* in_sizes, int n_in,
                              void* d_out, int out_size, void* d_ws, size_t ws_size,
                              hipStream_t stream) {
  const float* nfeat = (const float*)d_in[1];
  const float* w1    = (const float*)d_in[2];
  const float* b1    = (const float*)d_in[3];
  const float* w2    = (const float*)d_in[4];
  const float* b2    = (const float*)d_in[5];
  const float* g1    = (const float*)d_in[6];
  const float* bb1   = (const float*)d_in[7];
  const float* g2    = (const float*)d_in[8];
  const float* bb2   = (const float*)d_in[9];
  const float* g3    = (const float*)d_in[10];
  const float* bb3   = (const float*)d_in[11];
  const float* fcw   = (const float*)d_in[12];
  const float* fcb   = (const float*)d_in[13];
  const float* fow   = (const float*)d_in[14];
  const float* fob   = (const float*)d_in[15];
  const float* fcatw = (const float*)d_in[16];
  const float* fcatb = (const float*)d_in[17];
  const float* unif  = (const float*)d_in[18];
  float* ws  = (float*)d_ws;
  float* out = (float*)d_out;

  dgl_k4b_colsum<<<dim3(K5CH), dim3(384), 0, stream>>>(fcw, ws);
  dgl_k1_conv1_stats<<<dim3(375), dim3(320), 0, stream>>>(nfeat, w1, b1, ws);
  dgl_k2_fin1<<<dim3(1), dim3(64), 0, stream>>>(g1, bb1, ws);
  dgl_k3_conv2<<<dim3(K3LB, K3NB), dim3(256), 0, stream>>>(nfeat, w1, b1, w2, b2, ws);
  dgl_k4_fin2<<<dim3(1), dim3(512), 0, stream>>>(g2, bb2, ws);
  dgl_k5_fc<<<dim3(K5CH), dim3(512), 0, stream>>>(ws);
  dgl_k6_bn3<<<dim3(96), dim3(320), 0, stream>>>(fcb, g3, bb3, ws);
  dgl_k7_proj<<<dim3(307), dim3(192), 0, stream>>>(fow, ws);
  dgl_k8_edge<<<dim3(20, 20), dim3(256), 0, stream>>>(fob, fcatw, fcatb, unif, ws, out);
}

// Round 13
// 228.812 us; speedup vs baseline: 1.6333x; 1.0346x over previous
//
#include <hip/hip_runtime.h>
#include <hip/hip_fp16.h>

#define N_NODES 307
#define T_LEN   6000
#define L1      5991
#define L2      5982
#define ED      96
#define FDIM    95712
#define NCH2    16
#define LCPC    16                  // l-chunks per channel
#define CHL     374                 // rows per l-chunk (last = 372)
#define K5CH    (NCH2 * LCPC)       // 256 K-chunks, channel-pure
#define K3LB    94                  // K3 l-blocks (64 outputs each)
#define K3NB    20                  // K3 n-blocks (16 each)
#define K3BLKS  (K3LB * K3NB)       // 1880

// ---- workspace layout (float/u32 offsets) ---- (identical to R10..R12)
static const size_t WS_P1 = 256;                    // conv1 stat partials: 375*16
static const size_t WS_P2 = 8192;                   // conv2 stat partials: 1880*32
static const size_t WS_CS = 131072;                 // colsum partials: 256*96
static const size_t WS_NF = 155648;                 // node_feat 307*96
static const size_t WS_SP = 188416;                 // s_proj
static const size_t WS_RP = 221184;                 // r_proj
static const size_t WS_A2 = 262144;                 // a2 PACKED u32: 95712*320
static const size_t WS_FP = 262144 + 30627840ull;   // fc partials: 256*96*320
static const size_t WS_BP = 30889984ull + 7864320ull; // packed fcw u32: 95712*96
// total ~= 192.3 MB

typedef _Float16 half8 __attribute__((ext_vector_type(8)));
typedef float f32x4 __attribute__((ext_vector_type(4)));

union U4H8 { uint4 u; half8 h; };

// pack fp32 -> (f16 hi | f16 lo<<16), x ~= hi + lo/2048
__device__ __forceinline__ unsigned int pack2h(float x) {
  __half h = __float2half(x);
  float r = (x - __half2float(h)) * 2048.0f;
  __half l = __float2half(r);
  return (unsigned int)__half_as_ushort(h) | ((unsigned int)__half_as_ushort(l) << 16);
}

// split fp32 -> separate f16 hi / f16 lo words
__device__ __forceinline__ void split2h(float x, unsigned short& ho, unsigned short& lo) {
  __half h = __float2half(x);
  float r = (x - __half2float(h)) * 2048.0f;
  __half l = __float2half(r);
  ho = __half_as_ushort(h);
  lo = __half_as_ushort(l);
}

__device__ __forceinline__ void unpackU4(const uint4& a0, const uint4& a1,
                                         U4H8& hi, U4H8& lo) {
  hi.u = make_uint4((a0.x & 0xFFFFu) | (a0.y << 16), (a0.z & 0xFFFFu) | (a0.w << 16),
                    (a1.x & 0xFFFFu) | (a1.y << 16), (a1.z & 0xFFFFu) | (a1.w << 16));
  lo.u = make_uint4((a0.x >> 16) | (a0.y & 0xFFFF0000u), (a0.z >> 16) | (a0.w & 0xFFFF0000u),
                    (a1.x >> 16) | (a1.y & 0xFFFF0000u), (a1.z >> 16) | (a1.w & 0xFFFF0000u));
}

// K5 B-plane LDS swizzle (u16 index): row e (192 u16), XOR k-chunk by e&7.
__device__ __forceinline__ int swz16(int e, int k) {
  return e * 192 + (k ^ ((e & 7) << 3));
}

// ================= K1: conv1 + relu, channel stats only =================
__global__ __launch_bounds__(320) void dgl_k1_conv1_stats(
    const float* __restrict__ nfeat, const float* __restrict__ w1,
    const float* __restrict__ b1, float* __restrict__ ws) {
  __shared__ float sw1[80], sb1[8];
  __shared__ float sred[5][16];
  int tid = threadIdx.x;
  if (tid < 80) sw1[tid] = w1[tid];
  if (tid < 8)  sb1[tid] = b1[tid];
  __syncthreads();
  int l0 = blockIdx.x * 16;
  int n = tid;
  bool nv = n < N_NODES;
  float xx[26];
#pragma unroll
  for (int j = 0; j < 26; ++j) {
    int t = l0 + j;
    xx[j] = (nv && t < T_LEN) ? nfeat[(size_t)t * N_NODES + n] : 0.f;
  }
  float s[8], q[8];
#pragma unroll
  for (int c = 0; c < 8; ++c) { s[c] = 0.f; q[c] = 0.f; }
#pragma unroll
  for (int dl = 0; dl < 16; ++dl) {
    int l = l0 + dl;
    if (nv && l < L1) {
#pragma unroll
      for (int c = 0; c < 8; ++c) {
        float r = sb1[c];
#pragma unroll
        for (int k = 0; k < 10; ++k) r = fmaf(xx[dl + k], sw1[c * 10 + k], r);
        float z = fmaxf(r, 0.f);
        s[c] += z; q[c] += z * z;
      }
    }
  }
  int wv = tid >> 6, ln = tid & 63;
#pragma unroll
  for (int c = 0; c < 8; ++c) {
    float vs = s[c], vq = q[c];
    for (int o = 32; o; o >>= 1) { vs += __shfl_down(vs, o, 64); vq += __shfl_down(vq, o, 64); }
    if (ln == 0) { sred[wv][c] = vs; sred[wv][8 + c] = vq; }
  }
  __syncthreads();
  if (tid < 16) {
    float t = 0.f;
    for (int w = 0; w < 5; ++w) t += sred[w][tid];
    ws[WS_P1 + (size_t)blockIdx.x * 16 + tid] = t;
  }
}

// ================= K2: finalize bn1 =================
__global__ void dgl_k2_fin1(const float* __restrict__ g1, const float* __restrict__ b1,
                            float* __restrict__ ws) {
  __shared__ double sd[16];
  int tid = threadIdx.x;
  if (tid < 16) {
    double a = 0.0;
    for (int j = 0; j < 375; ++j) a += (double)ws[WS_P1 + (size_t)j * 16 + tid];
    sd[tid] = a;
  }
  __syncthreads();
  if (tid < 8) {
    double cnt = (double)N_NODES * (double)L1;
    double m = sd[tid] / cnt;
    double v = sd[tid + 8] / cnt - m * m;
    double inv = 1.0 / sqrt(v + 1e-5);
    ws[tid]     = (float)((double)g1[tid] * inv);
    ws[8 + tid] = (float)((double)b1[tid] - (double)g1[tid] * inv * m);
  }
}

// ================= K3 (MFMA, split planes): conv1+bn1 -> z1 f16-planes -> conv2 =================
// kk = k*8 + cin (pad 96). A = w2 planes [c2][kk]. B[n][kk] = z1 planes [pos][n'][cin].
// Fragment reads are direct b128 of 8 contiguous f16 -- no unpack VALU.
__global__ __launch_bounds__(256) void dgl_k3_conv2(
    const float* __restrict__ nfeat, const float* __restrict__ w1, const float* __restrict__ b1,
    const float* __restrict__ w2, const float* __restrict__ b2, float* __restrict__ ws) {
  __shared__ __align__(16) unsigned short z1h[75 * 128];  // 19.2 KB
  __shared__ __align__(16) unsigned short z1l[75 * 128];  // 19.2 KB
  __shared__ __align__(16) unsigned short w2h[16 * 96], w2l[16 * 96];
  __shared__ float sx[84 * 16];                           // [t-local][n]
  __shared__ float sw1[80], sb1[8], ss1[8], st1[8], sb2v[16];
  __shared__ float wps[4][4][4], wpq[4][4][4];
  int tid = threadIdx.x;
  int l0b = blockIdx.x * 64, n0 = blockIdx.y * 16;
  unsigned int* a2u = (unsigned int*)(ws + WS_A2);

  if (tid < 80) sw1[tid] = w1[tid];
  if (tid < 8)  { sb1[tid] = b1[tid]; ss1[tid] = ws[tid]; st1[tid] = ws[8 + tid]; }
  if (tid < 16) sb2v[tid] = b2[tid];
  for (int i = tid; i < 16 * 96; i += 256) {
    int c2 = i / 96, kk = i % 96;
    float v = (kk < 80) ? w2[c2 * 80 + (kk & 7) * 10 + (kk >> 3)] : 0.f;
    unsigned short ho, lo;
    split2h(v, ho, lo);
    w2h[i] = ho; w2l[i] = lo;
  }
  for (int i = tid; i < 84 * 16; i += 256) {
    int tl = i >> 4, nn = i & 15;
    int t = l0b + tl, n = n0 + nn;
    sx[i] = (t < T_LEN && n < N_NODES) ? nfeat[(size_t)t * N_NODES + n] : 0.f;
  }
  __syncthreads();
  // z1 build: 75 pos x 16 n x 8 cin -> split planes
  for (int i = tid; i < 9600; i += 256) {
    int lp = i >> 7, rem = i & 127;
    int n = rem >> 3, cin = rem & 7;
    float r = sb1[cin];
#pragma unroll
    for (int k = 0; k < 10; ++k) r = fmaf(sx[(lp + k) * 16 + n], sw1[cin * 10 + k], r);
    float z = fmaf(ss1[cin], fmaxf(r, 0.f), st1[cin]);
    unsigned short ho, lo;
    split2h(z, ho, lo);
    int idx = lp * 128 + ((n ^ (lp & 15)) << 3) + cin;
    z1h[idx] = ho; z1l[idx] = lo;
  }
  __syncthreads();

  int wv = tid >> 6, lane = tid & 63;
  int m = lane & 15, g = lane >> 4;
  U4H8 Ahi[3], Alo[3];
#pragma unroll
  for (int s = 0; s < 3; ++s) {
    Ahi[s].u = *(const uint4*)(&w2h[m * 96 + 32 * s + 8 * g]);
    Alo[s].u = *(const uint4*)(&w2l[m * 96 + 32 * s + 8 * g]);
  }
  float sv[4] = {0.f, 0.f, 0.f, 0.f}, qv[4] = {0.f, 0.f, 0.f, 0.f};
  int nglob = n0 + m;
  bool nok = nglob < N_NODES;
#pragma unroll 1
  for (int li = 0; li < 16; ++li) {
    int ll = 16 * wv + li;
    int lg = l0b + ll;
    f32x4 ac1 = (f32x4){0.f, 0.f, 0.f, 0.f};
    f32x4 ac2 = (f32x4){0.f, 0.f, 0.f, 0.f};
#pragma unroll
    for (int s = 0; s < 3; ++s) {
      int lp = ll + 4 * s + g;
      int bpidx = lp * 128 + ((m ^ (lp & 15)) << 3);
      U4H8 Bhi, Blo;
      Bhi.u = *(const uint4*)(&z1h[bpidx]);
      Blo.u = *(const uint4*)(&z1l[bpidx]);
      ac1 = __builtin_amdgcn_mfma_f32_16x16x32_f16(Ahi[s].h, Bhi.h, ac1, 0, 0, 0);
      ac2 = __builtin_amdgcn_mfma_f32_16x16x32_f16(Ahi[s].h, Blo.h, ac2, 0, 0, 0);
      ac2 = __builtin_amdgcn_mfma_f32_16x16x32_f16(Alo[s].h, Bhi.h, ac2, 0, 0, 0);
    }
    if (lg < L2) {
#pragma unroll
      for (int r = 0; r < 4; ++r) {
        float v = ac1[r] + ac2[r] * (1.0f / 2048.0f) + sb2v[4 * g + r];
        v = fmaxf(v, 0.f);
        if (!nok) v = 0.f;
        sv[r] += v; qv[r] += v * v;
        a2u[((size_t)(4 * g + r) * L2 + lg) * 320 + nglob] = pack2h(v);
      }
    }
  }
  // stats: reduce over the 16 m-lanes of each g-group (deterministic tree)
#pragma unroll
  for (int r = 0; r < 4; ++r) {
    for (int o = 1; o < 16; o <<= 1) {
      sv[r] += __shfl_xor(sv[r], o, 64);
      qv[r] += __shfl_xor(qv[r], o, 64);
    }
  }
  if (m == 0) {
#pragma unroll
    for (int r = 0; r < 4; ++r) { wps[wv][g][r] = sv[r]; wpq[wv][g][r] = qv[r]; }
  }
  __syncthreads();
  if (tid < 32) {
    int c2 = tid & 15; bool isq = tid >= 16;
    int gg = c2 >> 2, rr = c2 & 3;
    float t = 0.f;
    for (int w = 0; w < 4; ++w) t += isq ? wpq[w][gg][rr] : wps[w][gg][rr];
    ws[WS_P2 + ((size_t)blockIdx.y * gridDim.x + blockIdx.x) * 32 + tid] = t;
  }
}

// ================= K4: finalize bn2 =================
__global__ __launch_bounds__(512) void dgl_k4_fin2(const float* __restrict__ g2,
                                                   const float* __restrict__ b2,
                                                   float* __restrict__ ws) {
  __shared__ double dd[32][17];
  int tid = threadIdx.x;
  int v = tid >> 4, p = tid & 15;
  double a = 0.0;
  for (int j = p; j < K3BLKS; j += 16) a += (double)ws[WS_P2 + (size_t)j * 32 + v];
  dd[v][p] = a;
  __syncthreads();
  if (tid < 32) {
    double s = 0.0;
    for (int pp = 0; pp < 16; ++pp) s += dd[tid][pp];
    dd[tid][16] = s;
  }
  __syncthreads();
  if (tid < 16) {
    double cnt = (double)N_NODES * (double)L2;
    double m = dd[tid][16] / cnt;
    double var = dd[tid + 16][16] / cnt - m * m;
    double inv = 1.0 / sqrt(var + 1e-5);
    ws[16 + tid] = (float)((double)g2[tid] * inv);
    ws[32 + tid] = (float)((double)b2[tid] - (double)g2[tid] * inv * m);
  }
}

// ================= K4b: colsum partials of fc_w + packed fcw copy =================
__global__ __launch_bounds__(384) void dgl_k4b_colsum(const float* __restrict__ fcw,
                                                      float* __restrict__ ws) {
  __shared__ float red[4][96];
  int b = blockIdx.x;                 // 0..255
  int c = b / LCPC, lc = b % LCPC;
  int clen = (lc == LCPC - 1) ? (L2 - CHL * (LCPC - 1)) : CHL;
  size_t fb = (size_t)c * L2 + (size_t)lc * CHL;
  unsigned int* bpu = (unsigned int*)(ws + WS_BP);
  int tid = threadIdx.x, rg = tid / 96, e = tid % 96;
  float a = 0.f;
  for (int r = rg; r < clen; r += 4) {
    float v = fcw[(fb + r) * 96 + e];
    bpu[(fb + r) * 96 + e] = pack2h(v);
    a += v;
  }
  red[rg][e] = a;
  __syncthreads();
  if (tid < 96) {
    float t = red[0][tid] + red[1][tid] + red[2][tid] + red[3][tid];
    ws[WS_CS + (size_t)b * 96 + tid] = t;
  }
}

// ================= K5: one block per chunk, B in split f16 LDS planes, barrier-free K-loop =================
__global__ __launch_bounds__(512, 2) void dgl_k5_fc(float* __restrict__ ws) {
  __shared__ __align__(16) unsigned short Bh[96 * 192];   // 36 KB
  __shared__ __align__(16) unsigned short Bl[96 * 192];   // 36 KB
  int tid = threadIdx.x;
  int ch = blockIdx.x;                     // 0..255
  int lc = ch & (LCPC - 1);
  int clen = (lc == LCPC - 1) ? (L2 - CHL * (LCPC - 1)) : CHL;   // 372 or 374
  size_t fb = (size_t)(ch >> 4) * L2 + (size_t)lc * CHL;
  const unsigned int* a2u = (const unsigned int*)(ws + WS_A2);
  const unsigned int* bpu = (const unsigned int*)(ws + WS_BP);
  int wv = tid >> 6, lane = tid & 63;
  int m = lane & 15, g = lane >> 4;
  bool hasC = (wv + 16) < 20;

  f32x4 acc1[3][6], acc2[3][6];
#pragma unroll
  for (int s = 0; s < 3; ++s)
#pragma unroll
    for (int t = 0; t < 6; ++t) {
      acc1[s][t] = (f32x4){0.f, 0.f, 0.f, 0.f};
      acc2[s][t] = (f32x4){0.f, 0.f, 0.f, 0.f};
    }

#pragma unroll 1
  for (int half = 0; half < 2; ++half) {
    int kb0 = half * 192;
    // ---- stage B half: packed global -> split f16 planes (split once per element) ----
#pragma unroll 1
    for (int it = 0; it < 9; ++it) {
      int idx = tid + it * 512;            // < 4608 = 192 k x 24 e-groups(of 4)
      int r = idx % 192, eg = idx / 192;
      int rg = kb0 + r;
      uint4 v = (rg < clen) ? *(const uint4*)(bpu + (fb + rg) * 96 + eg * 4)
                            : make_uint4(0u, 0u, 0u, 0u);
      int e0 = eg * 4;
      Bh[swz16(e0 + 0, r)] = (unsigned short)(v.x & 0xFFFFu);
      Bl[swz16(e0 + 0, r)] = (unsigned short)(v.x >> 16);
      Bh[swz16(e0 + 1, r)] = (unsigned short)(v.y & 0xFFFFu);
      Bl[swz16(e0 + 1, r)] = (unsigned short)(v.y >> 16);
      Bh[swz16(e0 + 2, r)] = (unsigned short)(v.z & 0xFFFFu);
      Bl[swz16(e0 + 2, r)] = (unsigned short)(v.z >> 16);
      Bh[swz16(e0 + 3, r)] = (unsigned short)(v.w & 0xFFFFu);
      Bl[swz16(e0 + 3, r)] = (unsigned short)(v.w >> 16);
    }
    __syncthreads();
    // ---- 6 k32 steps, no barriers ----
#pragma unroll 1
    for (int ks = 0; ks < 6; ++ks) {
      int kbase = kb0 + ks * 32;
      int lim = clen - kbase;
      U4H8 Ahi[3], Alo[3];
#pragma unroll
      for (int s = 0; s < 3; ++s) {
        unsigned int au[8];
        if (s < 2 || hasC) {
          int nt = wv + s * 8;
          const unsigned int* abase =
              a2u + ((size_t)(fb + kbase + 8 * g)) * 320 + nt * 16 + m;
          if (lim >= 32) {
#pragma unroll
            for (int j = 0; j < 8; ++j) au[j] = abase[(size_t)j * 320];
          } else {
#pragma unroll
            for (int j = 0; j < 8; ++j) {
              int kk2 = 8 * g + j;
              au[j] = (kk2 < lim) ? abase[(size_t)j * 320] : 0u;
            }
          }
        } else {
#pragma unroll
          for (int j = 0; j < 8; ++j) au[j] = 0u;
        }
        uint4 a0 = make_uint4(au[0], au[1], au[2], au[3]);
        uint4 a1 = make_uint4(au[4], au[5], au[6], au[7]);
        unpackU4(a0, a1, Ahi[s], Alo[s]);
      }
#pragma unroll
      for (int t = 0; t < 6; ++t) {
        int e = 16 * t + m;
        int kl = ks * 32 + 8 * g;
        int kidx = swz16(e, kl);
        U4H8 Bhi, Blo;
        Bhi.u = *(const uint4*)(&Bh[kidx]);
        Blo.u = *(const uint4*)(&Bl[kidx]);
        acc1[0][t] = __builtin_amdgcn_mfma_f32_16x16x32_f16(Ahi[0].h, Bhi.h, acc1[0][t], 0, 0, 0);
        acc2[0][t] = __builtin_amdgcn_mfma_f32_16x16x32_f16(Ahi[0].h, Blo.h, acc2[0][t], 0, 0, 0);
        acc2[0][t] = __builtin_amdgcn_mfma_f32_16x16x32_f16(Alo[0].h, Bhi.h, acc2[0][t], 0, 0, 0);
        acc1[1][t] = __builtin_amdgcn_mfma_f32_16x16x32_f16(Ahi[1].h, Bhi.h, acc1[1][t], 0, 0, 0);
        acc2[1][t] = __builtin_amdgcn_mfma_f32_16x16x32_f16(Ahi[1].h, Blo.h, acc2[1][t], 0, 0, 0);
        acc2[1][t] = __builtin_amdgcn_mfma_f32_16x16x32_f16(Alo[1].h, Bhi.h, acc2[1][t], 0, 0, 0);
        if (hasC) {
          acc1[2][t] = __builtin_amdgcn_mfma_f32_16x16x32_f16(Ahi[2].h, Bhi.h, acc1[2][t], 0, 0, 0);
          acc2[2][t] = __builtin_amdgcn_mfma_f32_16x16x32_f16(Ahi[2].h, Blo.h, acc2[2][t], 0, 0, 0);
          acc2[2][t] = __builtin_amdgcn_mfma_f32_16x16x32_f16(Alo[2].h, Bhi.h, acc2[2][t], 0, 0, 0);
        }
      }
    }
    __syncthreads();
  }
  float* fp = ws + WS_FP;
#pragma unroll
  for (int s = 0; s < 3; ++s) {
    if (s < 2 || hasC) {
      int nt = wv + s * 8;
#pragma unroll
      for (int t = 0; t < 6; ++t) {
        int e = 16 * t + m;
        float4 o;
        o.x = acc1[s][t][0] + acc2[s][t][0] * (1.0f / 2048.0f);
        o.y = acc1[s][t][1] + acc2[s][t][1] * (1.0f / 2048.0f);
        o.z = acc1[s][t][2] + acc2[s][t][2] * (1.0f / 2048.0f);
        o.w = acc1[s][t][3] + acc2[s][t][3] * (1.0f / 2048.0f);
        *(float4*)(fp + ((size_t)ch * 96 + e) * 320 + nt * 16 + 4 * g) = o;
      }
    }
  }
}

// ================= K6: fp64 combine (s2*P + t2*colsum + fcb) + relu + bn3 =================
__global__ __launch_bounds__(320) void dgl_k6_bn3(const float* __restrict__ fcb,
                                                  const float* __restrict__ g3,
                                                  const float* __restrict__ b3,
                                                  float* __restrict__ ws) {
  int e = blockIdx.x, tid = threadIdx.x;
  __shared__ double s2d[16], csd[16];
  __shared__ double rs[5], rq[5];
  __shared__ float mb[2];
  if (tid < 16) {
    s2d[tid] = (double)ws[16 + tid];
    double a = 0.0;
#pragma unroll
    for (int lc = 0; lc < LCPC; ++lc)
      a += (double)ws[WS_CS + (size_t)(tid * LCPC + lc) * 96 + e];
    csd[tid] = a * (double)ws[32 + tid];
  }
  __syncthreads();
  const float* fp = ws + WS_FP;
  double a = 0.0;
#pragma unroll 2
  for (int c = 0; c < 16; ++c) {
    double pc = 0.0;
    for (int lc = 0; lc < LCPC; ++lc) {
      int ch = c * LCPC + lc;
      pc += (double)fp[((size_t)ch * 96 + e) * 320 + tid];
    }
    a += s2d[c] * pc;
  }
  double cst = 0.0;
#pragma unroll
  for (int c = 0; c < 16; ++c) cst += csd[c];
  float x = fmaxf((float)(a + cst) + fcb[e], 0.f);
  if (tid >= N_NODES) x = 0.f;
  double s = (double)x, q = (double)x * (double)x;
  int wv = tid >> 6, ln = tid & 63;
  for (int o = 32; o; o >>= 1) { s += __shfl_down(s, o, 64); q += __shfl_down(q, o, 64); }
  if (ln == 0) { rs[wv] = s; rq[wv] = q; }
  __syncthreads();
  if (tid == 0) {
    double S = 0.0, Q = 0.0;
    for (int w = 0; w < 5; ++w) { S += rs[w]; Q += rq[w]; }
    double m = S / (double)N_NODES;
    double var = Q / (double)N_NODES - m * m;
    mb[0] = (float)m; mb[1] = (float)(1.0 / sqrt(var + 1e-5));
  }
  __syncthreads();
  if (tid < N_NODES)
    ws[WS_NF + (size_t)tid * 96 + e] = g3[e] * (x - mb[0]) * mb[1] + b3[e];
}

// ================= K7: s_proj / r_proj =================
__global__ __launch_bounds__(192) void dgl_k7_proj(const float* __restrict__ fow,
                                                   float* __restrict__ ws) {
  __shared__ float sh[96];
  int nI = blockIdx.x, tid = threadIdx.x;
  if (tid < 96) sh[tid] = ws[WS_NF + (size_t)nI * 96 + tid];
  __syncthreads();
  int col = tid % 96, half = tid / 96;
  float a = 0.f;
#pragma unroll 8
  for (int d = 0; d < 96; ++d) a = fmaf(sh[d], fow[(size_t)(half * 96 + d) * 96 + col], a);
  ws[(half ? WS_RP : WS_SP) + (size_t)nI * 96 + col] = a;
}

// ================= K8: edge relu + logits + gumbel + hard argmax -> adj =================
__global__ __launch_bounds__(256) void dgl_k8_edge(const float* __restrict__ fob,
                                                   const float* __restrict__ fcatw,
                                                   const float* __restrict__ fcatb,
                                                   const float* __restrict__ unif,
                                                   const float* __restrict__ ws,
                                                   float* __restrict__ out) {
  __shared__ float rp[16][100], sp[16][100], bb[96], wa[96], wb[96];
  int tid = threadIdx.x;
  int i0 = blockIdx.y * 16, j0 = blockIdx.x * 16;
  for (int idx = tid; idx < 16 * 96; idx += 256) {
    int r = idx / 96, e = idx % 96;
    int ii = i0 + r, jj = j0 + r;
    rp[r][e] = (ii < N_NODES) ? ws[WS_RP + (size_t)ii * 96 + e] : 0.f;
    sp[r][e] = (jj < N_NODES) ? ws[WS_SP + (size_t)jj * 96 + e] : 0.f;
  }
  if (tid < 96) { bb[tid] = fob[tid]; wa[tid] = fcatw[2 * tid]; wb[tid] = fcatw[2 * tid + 1]; }
  __syncthreads();
  int il = tid >> 4, jl = tid & 15;
  int i = i0 + il, j = j0 + jl;
  float a0 = 0.f, a1 = 0.f;
#pragma unroll 4
  for (int e = 0; e < 96; ++e) {
    float ef = fmaxf(rp[il][e] + sp[jl][e] + bb[e], 0.f);
    a0 = fmaf(ef, wa[e], a0);
    a1 = fmaf(ef, wb[e], a1);
  }
  if (i < N_NODES && j < N_NODES) {
    size_t ue = ((size_t)i * N_NODES + j) * 2;
    float g0 = -logf(-logf(unif[ue] + 1e-20f) + 1e-20f);
    float g1 = -logf(-logf(unif[ue + 1] + 1e-20f) + 1e-20f);
    float z0 = a0 + fcatb[0] + g0;
    float z1 = a1 + fcatb[1] + g1;
    out[(size_t)i * N_NODES + j] = (i == j) ? 0.f : ((z0 >= z1) ? 1.f : 0.f);
  }
}

extern "C" void kernel_launch(void* const* d_in, const int* in_sizes, int n_in,
                              void* d_out, int out_size, void* d_ws, size_t ws_size,
                              hipStream_t stream) {
  const float* nfeat = (const float*)d_in[1];
  const float* w1    = (const float*)d_in[2];
  const float* b1    = (const float*)d_in[3];
  const float* w2    = (const float*)d_in[4];
  const float* b2    = (const float*)d_in[5];
  const float* g1    = (const float*)d_in[6];
  const float* bb1   = (const float*)d_in[7];
  const float* g2    = (const float*)d_in[8];
  const float* bb2   = (const float*)d_in[9];
  const float* g3    = (const float*)d_in[10];
  const float* bb3   = (const float*)d_in[11];
  const float* fcw   = (const float*)d_in[12];
  const float* fcb   = (const float*)d_in[13];
  const float* fow   = (const float*)d_in[14];
  const float* fob   = (const float*)d_in[15];
  const float* fcatw = (const float*)d_in[16];
  const float* fcatb = (const float*)d_in[17];
  const float* unif  = (const float*)d_in[18];
  float* ws  = (float*)d_ws;
  float* out = (float*)d_out;

  dgl_k4b_colsum<<<dim3(K5CH), dim3(384), 0, stream>>>(fcw, ws);
  dgl_k1_conv1_stats<<<dim3(375), dim3(320), 0, stream>>>(nfeat, w1, b1, ws);
  dgl_k2_fin1<<<dim3(1), dim3(64), 0, stream>>>(g1, bb1, ws);
  dgl_k3_conv2<<<dim3(K3LB, K3NB), dim3(256), 0, stream>>>(nfeat, w1, b1, w2, b2, ws);
  dgl_k4_fin2<<<dim3(1), dim3(512), 0, stream>>>(g2, bb2, ws);
  dgl_k5_fc<<<dim3(K5CH), dim3(512), 0, stream>>>(ws);
  dgl_k6_bn3<<<dim3(96), dim3(320), 0, stream>>>(fcb, g3, bb3, ws);
  dgl_k7_proj<<<dim3(307), dim3(192), 0, stream>>>(fow, ws);
  dgl_k8_edge<<<dim3(20, 20), dim3(256), 0, stream>>>(fob, fcatw, fcatb, unif, ws, out);
}